// Round 16
// baseline (1171.167 us; speedup 1.0000x reference)
//
#include <hip/hip_runtime.h>
#include <math.h>

namespace {

constexpr float ALPHA = 0.3f;
constexpr int B  = 16;
constexpr int N  = 1024;
constexpr int H  = 256;
constexpr int H2 = 512;
constexpr int NT = B * N;        // 16384 total nodes
constexpr int NE = N - 1;        // 1023 MST edges per batch
constexpr int CAP = 32;          // adjacency capacity per node (MST degree << 32)

__device__ __forceinline__ unsigned umin32(unsigned a, unsigned b) { return a < b ? a : b; }

typedef __attribute__((ext_vector_type(8))) short short8;
typedef __attribute__((ext_vector_type(4))) float f32x4;

// ---------------- row squared-norms: n2[row] = sum_k x[row][k]^2 ----------------
__global__ void n2_kernel(const float* __restrict__ x, float* __restrict__ n2) {
  int wave = threadIdx.x >> 6, lane = threadIdx.x & 63;
  int row  = blockIdx.x * 4 + wave;
  float4 v = *(const float4*)(x + (size_t)row * H + lane * 4);
  float s  = v.x * v.x + v.y * v.y + v.z * v.z + v.w * v.w;
  #pragma unroll
  for (int off = 32; off; off >>= 1) s += __shfl_xor(s, off);
  if (lane == 0) n2[row] = s;
}

// ------ distance matrix, symmetric upper-tri tiles; mirror via LDS transpose ----
// sh rows 0..15 = A-tile, 16..31 = B-tile during the K loop; the full [128][136]
// array is reused afterwards to transpose the output tile so the mirror write is
// contiguous float4 row-segments (bit-exact: same register values either way).
__global__ __launch_bounds__(256) void dist_kernel(const float* __restrict__ x,
    const float* __restrict__ n2, float* __restrict__ dist) {
  __shared__ float sh[128][136];
  const int bb = blockIdx.z;
  int idx = blockIdx.x, ti = 0;
  while (idx >= 8 - ti) { idx -= 8 - ti; ++ti; }
  const int tj = ti + idx;
  const int i0 = ti * 128, j0 = tj * 128;
  const int t = threadIdx.x, tx = t & 15, ty = t >> 4;
  const float* xb = x + (size_t)bb * N * H;
  float acc[8][8] = {};
  for (int kc = 0; kc < H; kc += 16) {
    #pragma unroll
    for (int u = 0; u < 2; ++u) {
      int q = t + u * 256;
      int row = q >> 2, kf = (q & 3) * 4;
      float4 a = *(const float4*)(xb + (size_t)(i0 + row) * H + kc + kf);
      sh[kf + 0][row] = a.x; sh[kf + 1][row] = a.y;
      sh[kf + 2][row] = a.z; sh[kf + 3][row] = a.w;
      float4 bv = *(const float4*)(xb + (size_t)(j0 + row) * H + kc + kf);
      sh[16 + kf + 0][row] = bv.x; sh[16 + kf + 1][row] = bv.y;
      sh[16 + kf + 2][row] = bv.z; sh[16 + kf + 3][row] = bv.w;
    }
    __syncthreads();
    #pragma unroll
    for (int kk = 0; kk < 16; ++kk) {
      float4 a0 = *(const float4*)&sh[kk][ty * 4];
      float4 a1 = *(const float4*)&sh[kk][64 + ty * 4];
      float4 b0 = *(const float4*)&sh[16 + kk][tx * 4];
      float4 b1 = *(const float4*)&sh[16 + kk][64 + tx * 4];
      float ar[8] = {a0.x,a0.y,a0.z,a0.w,a1.x,a1.y,a1.z,a1.w};
      float br[8] = {b0.x,b0.y,b0.z,b0.w,b1.x,b1.y,b1.z,b1.w};
      #pragma unroll
      for (int r = 0; r < 8; ++r)
        #pragma unroll
        for (int c = 0; c < 8; ++c) acc[r][c] += ar[r] * br[c];
    }
    __syncthreads();
  }
  float n2i[8], n2j[8];
  #pragma unroll
  for (int r = 0; r < 8; ++r)
    n2i[r] = n2[bb * N + i0 + (r < 4 ? ty * 4 + r : 64 + ty * 4 + r - 4)];
  #pragma unroll
  for (int c = 0; c < 8; ++c)
    n2j[c] = n2[bb * N + j0 + (c < 4 ? tx * 4 + c : 64 + tx * 4 + c - 4)];
  const bool mirror = (ti != tj);
  float* distb = dist + (size_t)bb * N * N;
  #pragma unroll
  for (int r = 0; r < 8; ++r) {
    int rl = (r < 4 ? ty * 4 + r : 64 + ty * 4 + r - 4);
    float o[8];
    #pragma unroll
    for (int c = 0; c < 8; ++c) {
      float d2 = (n2i[r] + n2j[c]) - 2.0f * acc[r][c];
      o[c] = sqrtf(fmaxf(d2, 0.0f));
    }
    float* dst = distb + (size_t)(i0 + rl) * N + j0;
    *(float4*)(dst + tx * 4)      = make_float4(o[0], o[1], o[2], o[3]);
    *(float4*)(dst + 64 + tx * 4) = make_float4(o[4], o[5], o[6], o[7]);
    if (mirror) {                                   // stash for transpose
      *(float4*)&sh[rl][tx * 4]      = make_float4(o[0], o[1], o[2], o[3]);
      *(float4*)&sh[rl][64 + tx * 4] = make_float4(o[4], o[5], o[6], o[7]);
    }
  }
  if (mirror) {
    __syncthreads();                                // o-tile fully in sh
    const int q = t >> 1, half = (t & 1) * 64;      // transposed row q, half of cols
    float* gdst = distb + (size_t)(j0 + q) * N + i0 + half;
    #pragma unroll
    for (int s = 0; s < 64; s += 4) {
      float4 v;
      v.x = sh[half + s + 0][q];
      v.y = sh[half + s + 1][q];
      v.z = sh[half + s + 2][q];
      v.w = sh[half + s + 3][q];
      *(float4*)(gdst + s) = v;
    }
  }
}

// ---------------- Prim helpers (R8/R13, proven) ----------------------------------
__device__ __forceinline__ unsigned wave_min_u32(unsigned x) {
  unsigned t;
  t = (unsigned)__builtin_amdgcn_update_dpp((int)x, (int)x, 0x111, 0xf, 0xf, false); x = umin32(x, t);
  t = (unsigned)__builtin_amdgcn_update_dpp((int)x, (int)x, 0x112, 0xf, 0xf, false); x = umin32(x, t);
  t = (unsigned)__builtin_amdgcn_update_dpp((int)x, (int)x, 0x114, 0xf, 0xf, false); x = umin32(x, t);
  t = (unsigned)__builtin_amdgcn_update_dpp((int)x, (int)x, 0x118, 0xf, 0xf, false); x = umin32(x, t);
  x = umin32(x, (unsigned)__shfl_xor((int)x, 16));
  x = umin32(x, (unsigned)__shfl_xor((int)x, 32));
  return (unsigned)__builtin_amdgcn_readlane((int)x, 63);
}

struct Sel2 { unsigned w; int j; };

__device__ __forceinline__ Sel2 block_select(unsigned mw0, unsigned mw1,
    unsigned mw2, unsigned mw3, int wid, int lane, unsigned long long* smin) {
  unsigned lm = umin32(umin32(mw0, mw1), umin32(mw2, mw3));
  unsigned wm = wave_min_u32(lm);
  unsigned mb = (mw0 == wm ? 1u : 0u) | (mw1 == wm ? 2u : 0u) |
                (mw2 == wm ? 4u : 0u) | (mw3 == wm ? 8u : 0u);
  unsigned long long bal = __ballot(mb != 0);
  int fl = __ffsll(bal) - 1;                         // lowest matching lane
  int slot = __ffs((unsigned)__builtin_amdgcn_readlane((int)mb, fl)) - 1;
  int widx = (wid << 8) | (fl << 2) | slot;          // lowest node id in wave
  if (lane == 0)
    smin[wid] = ((unsigned long long)wm << 32) | (unsigned)widx;
  __syncthreads();                                   // writes visible
  unsigned long long k0 = smin[0], k1 = smin[1], k2 = smin[2], k3 = smin[3];
  unsigned long long ka = k0 < k1 ? k0 : k1;
  unsigned long long kb = k2 < k3 ? k2 : k3;
  unsigned long long kk = ka < kb ? ka : kb;
  __syncthreads();                                   // reads done before next write
  Sel2 r; r.w = (unsigned)(kk >> 32); r.j = (int)(unsigned)(kk & 0xFFFFFFFFu);
  return r;
}

// ------- merged: blocks 0..15 = Prim MST + fused adjacency; 16.. = feat @ W1 ----
// Adjacency is built from the LDS edge list (same k-ascending order and fp
// accumulation order as the old adj_kernel -> bit-identical outputs).
__global__ __launch_bounds__(256) void prim_gemm1_kernel(
    const float* __restrict__ dist, const float* __restrict__ feat,
    const float* __restrict__ W1, int* __restrict__ adjI, float* __restrict__ adjW,
    int* __restrict__ cnt, float* __restrict__ dinv, float* __restrict__ y) {
  __shared__ unsigned long long smin[4];
  __shared__ int epv[NE];
  __shared__ int evv[NE];
  __shared__ float ews[NE];
  __shared__ float As[16][132], Bs[16][132];
  if (blockIdx.x < B) {
    // ==================== Prim path (R13, byte-identical loop) ====================
    const int b = blockIdx.x;
    const int tid = threadIdx.x, wid = tid >> 6, lane = tid & 63;
    const float* Db = dist + (size_t)b * N * N;
    const int jbase = tid * 4;                        // this thread's 4 nodes

    unsigned d0, d1, d2, d3;
    {
      float4 v = *(const float4*)(Db + jbase);        // row 0
      d0 = __float_as_uint(v.x); d1 = __float_as_uint(v.y);
      d2 = __float_as_uint(v.z); d3 = __float_as_uint(v.w);
    }
    unsigned mw0 = d0, mw1 = d1, mw2 = d2, mw3 = d3;
    unsigned rm0 = 0, rm1 = 0, rm2 = 0, rm3 = 0;
    int pa0 = 0, pa1 = 0, pa2 = 0, pa3 = 0;
    if (tid == 0) { rm0 = ~0u; mw0 = ~0u; }           // node 0 in tree

    Sel2 s0 = block_select(mw0, mw1, mw2, mw3, wid, lane, smin);
    int cj = s0.j;
    if ((cj >> 2) == tid) {
      int sl = cj & 3;
      int pv = pa0; if (sl == 1) pv = pa1; if (sl == 2) pv = pa2; if (sl == 3) pv = pa3;
      epv[0] = pv; evv[0] = cj; ews[0] = __uint_as_float(s0.w);
      if (sl == 0) { rm0 = ~0u; mw0 = ~0u; }
      if (sl == 1) { rm1 = ~0u; mw1 = ~0u; }
      if (sl == 2) { rm2 = ~0u; mw2 = ~0u; }
      if (sl == 3) { rm3 = ~0u; mw3 = ~0u; }
    }
    float4 xq = *(const float4*)(Db + (size_t)cj * N + jbase);

    for (int k = 1; k < NE; ++k) {
      unsigned r0 = __float_as_uint(xq.x), r1 = __float_as_uint(xq.y);
      unsigned r2 = __float_as_uint(xq.z), r3 = __float_as_uint(xq.w);
      unsigned q0 = r0 | rm0, q1 = r1 | rm1, q2 = r2 | rm2, q3 = r3 | rm3;
      mw0 = umin32(mw0, q0); mw1 = umin32(mw1, q1);
      mw2 = umin32(mw2, q2); mw3 = umin32(mw3, q3);
      Sel2 se = block_select(mw0, mw1, mw2, mw3, wid, lane, smin);
      const int nj = se.j;
      float4 nxt = *(const float4*)(Db + (size_t)nj * N + jbase);
      if (r0 < d0) { pa0 = cj; d0 = r0; }             // strict <, matches reference
      if (r1 < d1) { pa1 = cj; d1 = r1; }
      if (r2 < d2) { pa2 = cj; d2 = r2; }
      if (r3 < d3) { pa3 = cj; d3 = r3; }
      if ((nj >> 2) == tid) {                         // owner: emit + mask
        int sl = nj & 3;
        int pv = pa0; if (sl == 1) pv = pa1; if (sl == 2) pv = pa2; if (sl == 3) pv = pa3;
        epv[k] = pv; evv[k] = nj; ews[k] = __uint_as_float(se.w);
        if (sl == 0) { rm0 = ~0u; mw0 = ~0u; }
        if (sl == 1) { rm1 = ~0u; mw1 = ~0u; }
        if (sl == 2) { rm2 = ~0u; mw2 = ~0u; }
        if (sl == 3) { rm3 = ~0u; mw3 = ~0u; }
      }
      cj = nj; xq = nxt;
    }

    __syncthreads();                                  // epv/evv/ews visible
    // ---- fused adjacency: one pass over the LDS edge list, 4 nodes/thread ----
    {
      const int base = b << 10;
      const int l0 = jbase, l1 = jbase + 1, l2 = jbase + 2, l3 = jbase + 3;
      int c0 = 0, c1 = 0, c2 = 0, c3 = 0;
      float ws0 = 0.f, ws1 = 0.f, ws2 = 0.f, ws3 = 0.f;
      for (int k = 0; k < NE; ++k) {
        int p = epv[k], v = evv[k];
        float w = ews[k];
        if (p == l0 || v == l0) { ws0 += w; if (c0 < CAP) { int nb = (p == l0) ? v : p;
            adjI[(size_t)(base + l0) * CAP + c0] = base + nb;
            adjW[(size_t)(base + l0) * CAP + c0] = w; } ++c0; }
        if (p == l1 || v == l1) { ws1 += w; if (c1 < CAP) { int nb = (p == l1) ? v : p;
            adjI[(size_t)(base + l1) * CAP + c1] = base + nb;
            adjW[(size_t)(base + l1) * CAP + c1] = w; } ++c1; }
        if (p == l2 || v == l2) { ws2 += w; if (c2 < CAP) { int nb = (p == l2) ? v : p;
            adjI[(size_t)(base + l2) * CAP + c2] = base + nb;
            adjW[(size_t)(base + l2) * CAP + c2] = w; } ++c2; }
        if (p == l3 || v == l3) { ws3 += w; if (c3 < CAP) { int nb = (p == l3) ? v : p;
            adjI[(size_t)(base + l3) * CAP + c3] = base + nb;
            adjW[(size_t)(base + l3) * CAP + c3] = w; } ++c3; }
      }
      cnt[base + l0] = c0 < CAP ? c0 : CAP;  dinv[base + l0] = 1.0f / sqrtf(ws0 + 1.0f);
      cnt[base + l1] = c1 < CAP ? c1 : CAP;  dinv[base + l1] = 1.0f / sqrtf(ws1 + 1.0f);
      cnt[base + l2] = c2 < CAP ? c2 : CAP;  dinv[base + l2] = 1.0f / sqrtf(ws2 + 1.0f);
      cnt[base + l3] = c3 < CAP ? c3 : CAP;  dinv[base + l3] = 1.0f / sqrtf(ws3 + 1.0f);
    }
  } else {
    // ==================== gemm1 path: y = feat @ W1 (raw, K=256) ==================
    const int gb = blockIdx.x - B;
    const int m0 = (gb >> 2) * 128, n0 = (gb & 3) * 128;
    const int t = threadIdx.x, tx = t & 15, ty = t >> 4;
    float acc[8][8] = {};
    for (int kc = 0; kc < H; kc += 16) {
      #pragma unroll
      for (int u = 0; u < 2; ++u) {
        int q = t + u * 256;
        int row = q >> 2, kf = (q & 3) * 4;
        float4 a = *(const float4*)(feat + (size_t)(m0 + row) * H + kc + kf);
        As[kf + 0][row] = a.x; As[kf + 1][row] = a.y;
        As[kf + 2][row] = a.z; As[kf + 3][row] = a.w;
        int rowB = q >> 5, cf = (q & 31) * 4;
        *(float4*)&Bs[rowB][cf] = *(const float4*)(W1 + (size_t)(kc + rowB) * H2 + n0 + cf);
      }
      __syncthreads();
      #pragma unroll
      for (int kk = 0; kk < 16; ++kk) {
        float4 a0 = *(const float4*)&As[kk][ty * 4];
        float4 a1 = *(const float4*)&As[kk][64 + ty * 4];
        float4 b0 = *(const float4*)&Bs[kk][tx * 4];
        float4 b1 = *(const float4*)&Bs[kk][64 + tx * 4];
        float ar[8] = {a0.x,a0.y,a0.z,a0.w,a1.x,a1.y,a1.z,a1.w};
        float br[8] = {b0.x,b0.y,b0.z,b0.w,b1.x,b1.y,b1.z,b1.w};
        #pragma unroll
        for (int r = 0; r < 8; ++r)
          #pragma unroll
          for (int c = 0; c < 8; ++c) acc[r][c] += ar[r] * br[c];
      }
      __syncthreads();
    }
    #pragma unroll
    for (int r = 0; r < 8; ++r) {
      int m = m0 + (r < 4 ? ty * 4 + r : 64 + ty * 4 + r - 4);
      float* dst = y + (size_t)m * H2 + n0;
      *(float4*)(dst + tx * 4)      = make_float4(acc[r][0], acc[r][1], acc[r][2], acc[r][3]);
      *(float4*)(dst + 64 + tx * 4) = make_float4(acc[r][4], acc[r][5], acc[r][6], acc[r][7]);
    }
  }
}

// ------ finish layer 1: out1 = tanh(alpha*y + (1-alpha)*A_hat y + b1) -----------
__global__ void finish1_kernel(const float* __restrict__ y, const int* __restrict__ adjI,
    const float* __restrict__ adjW, const int* __restrict__ cnt,
    const float* __restrict__ dinv, const float* __restrict__ b1,
    float* __restrict__ out1) {
  int wave = threadIdx.x >> 6, lane = threadIdx.x & 63;
  int i = blockIdx.x * 4 + wave;
  float dv = dinv[i];
  int c = cnt[i];
  float selfc = ALPHA + (1.0f - ALPHA) * dv * dv;
  float4 acc[2];
  const float* yi = y + (size_t)i * H2 + lane * 4;
  #pragma unroll
  for (int u = 0; u < 2; ++u) {
    float4 v = *(const float4*)(yi + u * 256);
    acc[u].x = selfc * v.x; acc[u].y = selfc * v.y;
    acc[u].z = selfc * v.z; acc[u].w = selfc * v.w;
  }
  for (int e = 0; e < c; ++e) {
    int j   = adjI[i * CAP + e];
    float w = adjW[i * CAP + e];
    float coef = (1.0f - ALPHA) * dv * (w * dinv[j]);
    const float* yj = y + (size_t)j * H2 + lane * 4;
    #pragma unroll
    for (int u = 0; u < 2; ++u) {
      float4 v = *(const float4*)(yj + u * 256);
      acc[u].x += coef * v.x; acc[u].y += coef * v.y;
      acc[u].z += coef * v.z; acc[u].w += coef * v.w;
    }
  }
  float* ho = out1 + (size_t)i * H2 + lane * 4;
  #pragma unroll
  for (int u = 0; u < 2; ++u) {
    float4 bb = *(const float4*)(b1 + lane * 4 + u * 256);
    float4 o;
    o.x = tanhf(acc[u].x + bb.x); o.y = tanhf(acc[u].y + bb.y);
    o.z = tanhf(acc[u].z + bb.z); o.w = tanhf(acc[u].w + bb.w);
    *(float4*)(ho + u * 256) = o;
  }
}

// ---------------- SSG propagation: h = alpha*x + (1-alpha)*A_hat x --------------
template <int HH>
__global__ void prop_kernel(const float* __restrict__ x, const int* __restrict__ adjI,
    const float* __restrict__ adjW, const int* __restrict__ cnt,
    const float* __restrict__ dinv, float* __restrict__ h) {
  constexpr int U = HH / 256;
  int wave = threadIdx.x >> 6, lane = threadIdx.x & 63;
  int i = blockIdx.x * 4 + wave;
  float dv = dinv[i];
  int c = cnt[i];
  float selfc = ALPHA + (1.0f - ALPHA) * dv * dv;
  float4 acc[U];
  const float* xi = x + (size_t)i * HH + lane * 4;
  #pragma unroll
  for (int u = 0; u < U; ++u) {
    float4 v = *(const float4*)(xi + u * 256);
    acc[u].x = selfc * v.x; acc[u].y = selfc * v.y;
    acc[u].z = selfc * v.z; acc[u].w = selfc * v.w;
  }
  for (int e = 0; e < c; ++e) {
    int j   = adjI[i * CAP + e];
    float w = adjW[i * CAP + e];
    float coef = (1.0f - ALPHA) * dv * (w * dinv[j]);
    const float* xj = x + (size_t)j * HH + lane * 4;
    #pragma unroll
    for (int u = 0; u < U; ++u) {
      float4 v = *(const float4*)(xj + u * 256);
      acc[u].x += coef * v.x; acc[u].y += coef * v.y;
      acc[u].z += coef * v.z; acc[u].w += coef * v.w;
    }
  }
  float* ho = h + (size_t)i * HH + lane * 4;
  #pragma unroll
  for (int u = 0; u < U; ++u) *(float4*)(ho + u * 256) = acc[u];
}

// ---- split fp32 -> (hi, lo) bf16 (truncation; a - hi is exact in fp32) ---------
__device__ __forceinline__ void bf16split(float a, unsigned short& hi, unsigned short& lo) {
  unsigned u = __float_as_uint(a);
  hi = (unsigned short)(u >> 16);
  float fh = __uint_as_float(u & 0xFFFF0000u);
  float fl = a - fh;
  lo = (unsigned short)(__float_as_uint(fl) >> 16);
}

// ---- MFMA split-bf16 GEMM + bias + tanh (R15, proven) --------------------------
__global__ __launch_bounds__(256) void mgemm_tanh_kernel(const float* __restrict__ A,
    const float* __restrict__ W, const float* __restrict__ bias, float* __restrict__ C) {
  __shared__ unsigned short Ahi[128][40], Alo[128][40];   // [row][k]
  __shared__ unsigned short Bhi[128][40], Blo[128][40];   // [col][k] (W transposed)
  const int m0 = blockIdx.x * 128, n0 = blockIdx.y * 128;
  const int t = threadIdx.x;
  const int w = t >> 6, lane = t & 63;
  const int lrow = lane & 15, lk = (lane >> 4) * 8;
  f32x4 acc[2][8];
  #pragma unroll
  for (int mt = 0; mt < 2; ++mt)
    #pragma unroll
    for (int nt = 0; nt < 8; ++nt) acc[mt][nt] = (f32x4){0.f, 0.f, 0.f, 0.f};

  const int arow = t >> 1, akq = (t & 1) * 16;            // A staging coords
  const int wr = t & 31, wc4 = (t >> 5) * 16;             // W staging coords

  for (int kc = 0; kc < H2; kc += 32) {
    {
      const float* src = A + (size_t)(m0 + arow) * H2 + kc + akq;
      unsigned short h[16], l[16];
      #pragma unroll
      for (int i = 0; i < 16; i += 4) {
        float4 v = *(const float4*)(src + i);
        bf16split(v.x, h[i], l[i]);     bf16split(v.y, h[i+1], l[i+1]);
        bf16split(v.z, h[i+2], l[i+2]); bf16split(v.w, h[i+3], l[i+3]);
      }
      short8 ph0 = {(short)h[0],(short)h[1],(short)h[2],(short)h[3],
                    (short)h[4],(short)h[5],(short)h[6],(short)h[7]};
      short8 ph1 = {(short)h[8],(short)h[9],(short)h[10],(short)h[11],
                    (short)h[12],(short)h[13],(short)h[14],(short)h[15]};
      short8 pl0 = {(short)l[0],(short)l[1],(short)l[2],(short)l[3],
                    (short)l[4],(short)l[5],(short)l[6],(short)l[7]};
      short8 pl1 = {(short)l[8],(short)l[9],(short)l[10],(short)l[11],
                    (short)l[12],(short)l[13],(short)l[14],(short)l[15]};
      *(short8*)&Ahi[arow][akq]     = ph0;
      *(short8*)&Ahi[arow][akq + 8] = ph1;
      *(short8*)&Alo[arow][akq]     = pl0;
      *(short8*)&Alo[arow][akq + 8] = pl1;
    }
    {
      const float* wsrc = W + (size_t)(kc + wr) * H2 + n0 + wc4;
      #pragma unroll
      for (int i = 0; i < 16; i += 4) {
        float4 v = *(const float4*)(wsrc + i);
        unsigned short h0,h1,h2,h3,l0,l1,l2,l3;
        bf16split(v.x, h0, l0); bf16split(v.y, h1, l1);
        bf16split(v.z, h2, l2); bf16split(v.w, h3, l3);
        Bhi[wc4+i+0][wr] = h0; Bhi[wc4+i+1][wr] = h1;
        Bhi[wc4+i+2][wr] = h2; Bhi[wc4+i+3][wr] = h3;
        Blo[wc4+i+0][wr] = l0; Blo[wc4+i+1][wr] = l1;
        Blo[wc4+i+2][wr] = l2; Blo[wc4+i+3][wr] = l3;
      }
    }
    __syncthreads();
    const int r0 = w * 32 + lrow;
    short8 a0h = *(const short8*)&Ahi[r0][lk];
    short8 a0l = *(const short8*)&Alo[r0][lk];
    short8 a1h = *(const short8*)&Ahi[r0 + 16][lk];
    short8 a1l = *(const short8*)&Alo[r0 + 16][lk];
    #pragma unroll
    for (int nt = 0; nt < 8; ++nt) {
      short8 bh = *(const short8*)&Bhi[nt * 16 + lrow][lk];
      short8 bl = *(const short8*)&Blo[nt * 16 + lrow][lk];
      acc[0][nt] = __builtin_amdgcn_mfma_f32_16x16x32_bf16(a0h, bh, acc[0][nt], 0, 0, 0);
      acc[0][nt] = __builtin_amdgcn_mfma_f32_16x16x32_bf16(a0l, bh, acc[0][nt], 0, 0, 0);
      acc[0][nt] = __builtin_amdgcn_mfma_f32_16x16x32_bf16(a0h, bl, acc[0][nt], 0, 0, 0);
      acc[1][nt] = __builtin_amdgcn_mfma_f32_16x16x32_bf16(a1h, bh, acc[1][nt], 0, 0, 0);
      acc[1][nt] = __builtin_amdgcn_mfma_f32_16x16x32_bf16(a1l, bh, acc[1][nt], 0, 0, 0);
      acc[1][nt] = __builtin_amdgcn_mfma_f32_16x16x32_bf16(a1h, bl, acc[1][nt], 0, 0, 0);
    }
    __syncthreads();
  }
  #pragma unroll
  for (int mt = 0; mt < 2; ++mt) {
    #pragma unroll
    for (int nt = 0; nt < 8; ++nt) {
      int col = n0 + nt * 16 + lrow;
      float bcol = bias[col];
      #pragma unroll
      for (int i = 0; i < 4; ++i) {
        int row = m0 + w * 32 + mt * 16 + (lane >> 4) * 4 + i;
        C[(size_t)row * H2 + col] = tanhf(acc[mt][nt][i] + bcol);
      }
    }
  }
}

// ---------------- mean pool over N nodes per graph ------------------------------
__global__ void pool_kernel(const float* __restrict__ x, float* __restrict__ pooled) {
  int b = blockIdx.x;
  int c = blockIdx.y * 256 + threadIdx.x;
  const float* xb = x + ((size_t)b << 10) * H2 + c;
  float s = 0.0f;
  for (int i = 0; i < N; ++i) s += xb[(size_t)i * H2];
  pooled[b * H2 + c] = s * (1.0f / N);
}

// ---------------- dense head: tanh(pooled@Wd+bd) @ Wo + bo ----------------------
__global__ void head_kernel(const float* __restrict__ pooled, const float* __restrict__ Wd,
    const float* __restrict__ bd, const float* __restrict__ Wo, const float* __restrict__ bo,
    float* __restrict__ out) {
  __shared__ float sp[512], sh[256];
  int b = blockIdx.x, t = threadIdx.x;
  sp[t] = pooled[b * H2 + t];
  sp[t + 256] = pooled[b * H2 + t + 256];
  __syncthreads();
  float acc = bd[t];
  for (int c2 = 0; c2 < 512; ++c2) acc += sp[c2] * Wd[c2 * 256 + t];
  sh[t] = tanhf(acc);
  __syncthreads();
  if (t < 8) {
    float o = bo[t];
    for (int j = 0; j < 256; ++j) o += sh[j] * Wo[j * 8 + t];
    out[b * 8 + t] = o;
  }
}

}  // namespace

extern "C" void kernel_launch(void* const* d_in, const int* in_sizes, int n_in,
                              void* d_out, int out_size, void* d_ws, size_t ws_size,
                              hipStream_t stream) {
  const float* feat = (const float*)d_in[0];
  const float* W1 = (const float*)d_in[1];
  const float* b1 = (const float*)d_in[2];
  const float* W2 = (const float*)d_in[3];
  const float* b2 = (const float*)d_in[4];
  const float* W3 = (const float*)d_in[5];
  const float* b3 = (const float*)d_in[6];
  const float* Wd = (const float*)d_in[7];
  const float* bd = (const float*)d_in[8];
  const float* Wo = (const float*)d_in[9];
  const float* bo = (const float*)d_in[10];
  float* out = (float*)d_out;
  char* ws = (char*)d_ws;

  float* dist = (float*)(ws);
  float* out1 = (float*)(ws);
  float* x2   = (float*)(ws + ((size_t)32 << 20));
  float* x3   = (float*)(ws);
  float* ybuf = (float*)(ws + ((size_t)64 << 20));
  float* hbuf = (float*)(ws + ((size_t)64 << 20));
  char* misc  = ws + ((size_t)96 << 20);
  int*   cnt    = (int*)(misc + 196608);
  float* dinv   = (float*)(misc + 262144);
  int*   adjI   = (int*)(misc + 327680);
  float* adjW   = (float*)(misc + 327680 + 2097152);
  float* n2     = (float*)(misc + 327680 + 2 * 2097152);
  float* pooled = (float*)(misc + 327680 + 2 * 2097152 + 65536);

  n2_kernel<<<NT / 4, 256, 0, stream>>>(feat, n2);
  dist_kernel<<<dim3(36, 1, 16), 256, 0, stream>>>(feat, n2, dist);
  prim_gemm1_kernel<<<B + (NT / 128) * 4, 256, 0, stream>>>(
      dist, feat, W1, adjI, adjW, cnt, dinv, ybuf);

  finish1_kernel<<<NT / 4, 256, 0, stream>>>(ybuf, adjI, adjW, cnt, dinv, b1, out1);
  prop_kernel<512><<<NT / 4, 256, 0, stream>>>(out1, adjI, adjW, cnt, dinv, hbuf);
  mgemm_tanh_kernel<<<dim3(NT / 128, 4), 256, 0, stream>>>(hbuf, W2, b2, x2);
  prop_kernel<512><<<NT / 4, 256, 0, stream>>>(x2, adjI, adjW, cnt, dinv, hbuf);
  mgemm_tanh_kernel<<<dim3(NT / 128, 4), 256, 0, stream>>>(hbuf, W3, b3, x3);

  pool_kernel<<<dim3(B, H2 / 256), 256, 0, stream>>>(x3, pooled);
  head_kernel<<<B, 256, 0, stream>>>(pooled, Wd, bd, Wo, bo, out);
}

// Round 17
// 1125.845 us; speedup vs baseline: 1.0403x; 1.0403x over previous
//
#include <hip/hip_runtime.h>
#include <math.h>

namespace {

constexpr float ALPHA = 0.3f;
constexpr int B  = 16;
constexpr int N  = 1024;
constexpr int H  = 256;
constexpr int H2 = 512;
constexpr int NT = B * N;        // 16384 total nodes
constexpr int NE = N - 1;        // 1023 MST edges per batch
constexpr int CAP = 32;          // adjacency capacity per node (MST degree << 32)

__device__ __forceinline__ unsigned umin32(unsigned a, unsigned b) { return a < b ? a : b; }

typedef __attribute__((ext_vector_type(8))) short short8;
typedef __attribute__((ext_vector_type(4))) float f32x4;

// ---------------- row squared-norms: n2[row] = sum_k x[row][k]^2 ----------------
__global__ void n2_kernel(const float* __restrict__ x, float* __restrict__ n2) {
  int wave = threadIdx.x >> 6, lane = threadIdx.x & 63;
  int row  = blockIdx.x * 4 + wave;
  float4 v = *(const float4*)(x + (size_t)row * H + lane * 4);
  float s  = v.x * v.x + v.y * v.y + v.z * v.z + v.w * v.w;
  #pragma unroll
  for (int off = 32; off; off >>= 1) s += __shfl_xor(s, off);
  if (lane == 0) n2[row] = s;
}

// ------ distance matrix, symmetric upper-tri tiles; mirror via LDS transpose ----
// (R16, proven: ~90us faster than scattered mirror; bit-exact values)
__global__ __launch_bounds__(256) void dist_kernel(const float* __restrict__ x,
    const float* __restrict__ n2, float* __restrict__ dist) {
  __shared__ float sh[128][136];
  const int bb = blockIdx.z;
  int idx = blockIdx.x, ti = 0;
  while (idx >= 8 - ti) { idx -= 8 - ti; ++ti; }
  const int tj = ti + idx;
  const int i0 = ti * 128, j0 = tj * 128;
  const int t = threadIdx.x, tx = t & 15, ty = t >> 4;
  const float* xb = x + (size_t)bb * N * H;
  float acc[8][8] = {};
  for (int kc = 0; kc < H; kc += 16) {
    #pragma unroll
    for (int u = 0; u < 2; ++u) {
      int q = t + u * 256;
      int row = q >> 2, kf = (q & 3) * 4;
      float4 a = *(const float4*)(xb + (size_t)(i0 + row) * H + kc + kf);
      sh[kf + 0][row] = a.x; sh[kf + 1][row] = a.y;
      sh[kf + 2][row] = a.z; sh[kf + 3][row] = a.w;
      float4 bv = *(const float4*)(xb + (size_t)(j0 + row) * H + kc + kf);
      sh[16 + kf + 0][row] = bv.x; sh[16 + kf + 1][row] = bv.y;
      sh[16 + kf + 2][row] = bv.z; sh[16 + kf + 3][row] = bv.w;
    }
    __syncthreads();
    #pragma unroll
    for (int kk = 0; kk < 16; ++kk) {
      float4 a0 = *(const float4*)&sh[kk][ty * 4];
      float4 a1 = *(const float4*)&sh[kk][64 + ty * 4];
      float4 b0 = *(const float4*)&sh[16 + kk][tx * 4];
      float4 b1 = *(const float4*)&sh[16 + kk][64 + tx * 4];
      float ar[8] = {a0.x,a0.y,a0.z,a0.w,a1.x,a1.y,a1.z,a1.w};
      float br[8] = {b0.x,b0.y,b0.z,b0.w,b1.x,b1.y,b1.z,b1.w};
      #pragma unroll
      for (int r = 0; r < 8; ++r)
        #pragma unroll
        for (int c = 0; c < 8; ++c) acc[r][c] += ar[r] * br[c];
    }
    __syncthreads();
  }
  float n2i[8], n2j[8];
  #pragma unroll
  for (int r = 0; r < 8; ++r)
    n2i[r] = n2[bb * N + i0 + (r < 4 ? ty * 4 + r : 64 + ty * 4 + r - 4)];
  #pragma unroll
  for (int c = 0; c < 8; ++c)
    n2j[c] = n2[bb * N + j0 + (c < 4 ? tx * 4 + c : 64 + tx * 4 + c - 4)];
  const bool mirror = (ti != tj);
  float* distb = dist + (size_t)bb * N * N;
  #pragma unroll
  for (int r = 0; r < 8; ++r) {
    int rl = (r < 4 ? ty * 4 + r : 64 + ty * 4 + r - 4);
    float o[8];
    #pragma unroll
    for (int c = 0; c < 8; ++c) {
      float d2 = (n2i[r] + n2j[c]) - 2.0f * acc[r][c];
      o[c] = sqrtf(fmaxf(d2, 0.0f));
    }
    float* dst = distb + (size_t)(i0 + rl) * N + j0;
    *(float4*)(dst + tx * 4)      = make_float4(o[0], o[1], o[2], o[3]);
    *(float4*)(dst + 64 + tx * 4) = make_float4(o[4], o[5], o[6], o[7]);
    if (mirror) {                                   // stash for transpose
      *(float4*)&sh[rl][tx * 4]      = make_float4(o[0], o[1], o[2], o[3]);
      *(float4*)&sh[rl][64 + tx * 4] = make_float4(o[4], o[5], o[6], o[7]);
    }
  }
  if (mirror) {
    __syncthreads();                                // o-tile fully in sh
    const int q = t >> 1, half = (t & 1) * 64;      // transposed row q, half of cols
    float* gdst = distb + (size_t)(j0 + q) * N + i0 + half;
    #pragma unroll
    for (int s = 0; s < 64; s += 4) {
      float4 v;
      v.x = sh[half + s + 0][q];
      v.y = sh[half + s + 1][q];
      v.z = sh[half + s + 2][q];
      v.w = sh[half + s + 3][q];
      *(float4*)(gdst + s) = v;
    }
  }
}

// ---------------- Prim helpers (R8/R13, proven) ----------------------------------
__device__ __forceinline__ unsigned wave_min_u32(unsigned x) {
  unsigned t;
  t = (unsigned)__builtin_amdgcn_update_dpp((int)x, (int)x, 0x111, 0xf, 0xf, false); x = umin32(x, t);
  t = (unsigned)__builtin_amdgcn_update_dpp((int)x, (int)x, 0x112, 0xf, 0xf, false); x = umin32(x, t);
  t = (unsigned)__builtin_amdgcn_update_dpp((int)x, (int)x, 0x114, 0xf, 0xf, false); x = umin32(x, t);
  t = (unsigned)__builtin_amdgcn_update_dpp((int)x, (int)x, 0x118, 0xf, 0xf, false); x = umin32(x, t);
  x = umin32(x, (unsigned)__shfl_xor((int)x, 16));
  x = umin32(x, (unsigned)__shfl_xor((int)x, 32));
  return (unsigned)__builtin_amdgcn_readlane((int)x, 63);
}

struct Sel2 { unsigned w; int j; };

__device__ __forceinline__ Sel2 block_select(unsigned mw0, unsigned mw1,
    unsigned mw2, unsigned mw3, int wid, int lane, unsigned long long* smin) {
  unsigned lm = umin32(umin32(mw0, mw1), umin32(mw2, mw3));
  unsigned wm = wave_min_u32(lm);
  unsigned mb = (mw0 == wm ? 1u : 0u) | (mw1 == wm ? 2u : 0u) |
                (mw2 == wm ? 4u : 0u) | (mw3 == wm ? 8u : 0u);
  unsigned long long bal = __ballot(mb != 0);
  int fl = __ffsll(bal) - 1;                         // lowest matching lane
  int slot = __ffs((unsigned)__builtin_amdgcn_readlane((int)mb, fl)) - 1;
  int widx = (wid << 8) | (fl << 2) | slot;          // lowest node id in wave
  if (lane == 0)
    smin[wid] = ((unsigned long long)wm << 32) | (unsigned)widx;
  __syncthreads();                                   // writes visible
  unsigned long long k0 = smin[0], k1 = smin[1], k2 = smin[2], k3 = smin[3];
  unsigned long long ka = k0 < k1 ? k0 : k1;
  unsigned long long kb = k2 < k3 ? k2 : k3;
  unsigned long long kk = ka < kb ? ka : kb;
  __syncthreads();                                   // reads done before next write
  Sel2 r; r.w = (unsigned)(kk >> 32); r.j = (int)(unsigned)(kk & 0xFFFFFFFFu);
  return r;
}

// ------- merged: blocks 0..15 = Prim MST (R13/R15, proven); 16.. = feat @ W1 ----
__global__ __launch_bounds__(256) void prim_gemm1_kernel(
    const float* __restrict__ dist, const float* __restrict__ feat,
    const float* __restrict__ W1, int* __restrict__ ep, int* __restrict__ ev,
    float* __restrict__ ewt, float* __restrict__ y) {
  __shared__ unsigned long long smin[4];
  __shared__ int epv[NE];
  __shared__ int evv[NE];
  __shared__ float ews[NE];
  __shared__ float As[16][132], Bs[16][132];
  if (blockIdx.x < B) {
    // ==================== Prim path (R13, byte-identical) ====================
    const int b = blockIdx.x;
    const int tid = threadIdx.x, wid = tid >> 6, lane = tid & 63;
    const float* Db = dist + (size_t)b * N * N;
    const int jbase = tid * 4;                        // this thread's 4 nodes

    unsigned d0, d1, d2, d3;
    {
      float4 v = *(const float4*)(Db + jbase);        // row 0
      d0 = __float_as_uint(v.x); d1 = __float_as_uint(v.y);
      d2 = __float_as_uint(v.z); d3 = __float_as_uint(v.w);
    }
    unsigned mw0 = d0, mw1 = d1, mw2 = d2, mw3 = d3;
    unsigned rm0 = 0, rm1 = 0, rm2 = 0, rm3 = 0;
    int pa0 = 0, pa1 = 0, pa2 = 0, pa3 = 0;
    if (tid == 0) { rm0 = ~0u; mw0 = ~0u; }           // node 0 in tree

    Sel2 s0 = block_select(mw0, mw1, mw2, mw3, wid, lane, smin);
    int cj = s0.j;
    if ((cj >> 2) == tid) {
      int sl = cj & 3;
      int pv = pa0; if (sl == 1) pv = pa1; if (sl == 2) pv = pa2; if (sl == 3) pv = pa3;
      epv[0] = pv; evv[0] = cj; ews[0] = __uint_as_float(s0.w);
      if (sl == 0) { rm0 = ~0u; mw0 = ~0u; }
      if (sl == 1) { rm1 = ~0u; mw1 = ~0u; }
      if (sl == 2) { rm2 = ~0u; mw2 = ~0u; }
      if (sl == 3) { rm3 = ~0u; mw3 = ~0u; }
    }
    float4 xq = *(const float4*)(Db + (size_t)cj * N + jbase);

    for (int k = 1; k < NE; ++k) {
      unsigned r0 = __float_as_uint(xq.x), r1 = __float_as_uint(xq.y);
      unsigned r2 = __float_as_uint(xq.z), r3 = __float_as_uint(xq.w);
      unsigned q0 = r0 | rm0, q1 = r1 | rm1, q2 = r2 | rm2, q3 = r3 | rm3;
      mw0 = umin32(mw0, q0); mw1 = umin32(mw1, q1);
      mw2 = umin32(mw2, q2); mw3 = umin32(mw3, q3);
      Sel2 se = block_select(mw0, mw1, mw2, mw3, wid, lane, smin);
      const int nj = se.j;
      float4 nxt = *(const float4*)(Db + (size_t)nj * N + jbase);
      if (r0 < d0) { pa0 = cj; d0 = r0; }             // strict <, matches reference
      if (r1 < d1) { pa1 = cj; d1 = r1; }
      if (r2 < d2) { pa2 = cj; d2 = r2; }
      if (r3 < d3) { pa3 = cj; d3 = r3; }
      if ((nj >> 2) == tid) {                         // owner: emit + mask
        int sl = nj & 3;
        int pv = pa0; if (sl == 1) pv = pa1; if (sl == 2) pv = pa2; if (sl == 3) pv = pa3;
        epv[k] = pv; evv[k] = nj; ews[k] = __uint_as_float(se.w);
        if (sl == 0) { rm0 = ~0u; mw0 = ~0u; }
        if (sl == 1) { rm1 = ~0u; mw1 = ~0u; }
        if (sl == 2) { rm2 = ~0u; mw2 = ~0u; }
        if (sl == 3) { rm3 = ~0u; mw3 = ~0u; }
      }
      cj = nj; xq = nxt;
    }

    __syncthreads();                                  // epv/evv/ews visible
    for (int e = tid; e < NE; e += 256) {
      ep[b * NE + e]  = epv[e];
      ev[b * NE + e]  = evv[e];
      ewt[b * NE + e] = ews[e];
    }
  } else {
    // ==================== gemm1 path: y = feat @ W1 (raw, K=256) ==================
    const int gb = blockIdx.x - B;
    const int m0 = (gb >> 2) * 128, n0 = (gb & 3) * 128;
    const int t = threadIdx.x, tx = t & 15, ty = t >> 4;
    float acc[8][8] = {};
    for (int kc = 0; kc < H; kc += 16) {
      #pragma unroll
      for (int u = 0; u < 2; ++u) {
        int q = t + u * 256;
        int row = q >> 2, kf = (q & 3) * 4;
        float4 a = *(const float4*)(feat + (size_t)(m0 + row) * H + kc + kf);
        As[kf + 0][row] = a.x; As[kf + 1][row] = a.y;
        As[kf + 2][row] = a.z; As[kf + 3][row] = a.w;
        int rowB = q >> 5, cf = (q & 31) * 4;
        *(float4*)&Bs[rowB][cf] = *(const float4*)(W1 + (size_t)(kc + rowB) * H2 + n0 + cf);
      }
      __syncthreads();
      #pragma unroll
      for (int kk = 0; kk < 16; ++kk) {
        float4 a0 = *(const float4*)&As[kk][ty * 4];
        float4 a1 = *(const float4*)&As[kk][64 + ty * 4];
        float4 b0 = *(const float4*)&Bs[kk][tx * 4];
        float4 b1 = *(const float4*)&Bs[kk][64 + tx * 4];
        float ar[8] = {a0.x,a0.y,a0.z,a0.w,a1.x,a1.y,a1.z,a1.w};
        float br[8] = {b0.x,b0.y,b0.z,b0.w,b1.x,b1.y,b1.z,b1.w};
        #pragma unroll
        for (int r = 0; r < 8; ++r)
          #pragma unroll
          for (int c = 0; c < 8; ++c) acc[r][c] += ar[r] * br[c];
      }
      __syncthreads();
    }
    #pragma unroll
    for (int r = 0; r < 8; ++r) {
      int m = m0 + (r < 4 ? ty * 4 + r : 64 + ty * 4 + r - 4);
      float* dst = y + (size_t)m * H2 + n0;
      *(float4*)(dst + tx * 4)      = make_float4(acc[r][0], acc[r][1], acc[r][2], acc[r][3]);
      *(float4*)(dst + 64 + tx * 4) = make_float4(acc[r][4], acc[r][5], acc[r][6], acc[r][7]);
    }
  }
}

// ---------------- adjacency + deg^-1/2 (R15, proven; 64-block parallel) ---------
__global__ void adj_kernel(const int* __restrict__ ep, const int* __restrict__ ev,
    const float* __restrict__ ewt, int* __restrict__ adjI, float* __restrict__ adjW,
    int* __restrict__ cnt, float* __restrict__ dinv) {
  int i = blockIdx.x * 256 + threadIdx.x;
  int b = i >> 10, loc = i & 1023;
  const int* epb = ep + b * NE;
  const int* evb = ev + b * NE;
  const float* ewb = ewt + b * NE;
  int c = 0; float wsum = 0.0f;
  for (int k = 0; k < NE; ++k) {
    int p = epb[k], v = evb[k];
    if (p == loc || v == loc) {
      float w = ewb[k];
      wsum += w;
      int nb = (p == loc) ? v : p;
      if (c < CAP) { adjI[i * CAP + c] = (b << 10) + nb; adjW[i * CAP + c] = w; }
      ++c;
    }
  }
  cnt[i]  = c < CAP ? c : CAP;
  dinv[i] = 1.0f / sqrtf(wsum + 1.0f);
}

// ------ finish layer 1: out1 = tanh(alpha*y + (1-alpha)*A_hat y + b1) -----------
__global__ void finish1_kernel(const float* __restrict__ y, const int* __restrict__ adjI,
    const float* __restrict__ adjW, const int* __restrict__ cnt,
    const float* __restrict__ dinv, const float* __restrict__ b1,
    float* __restrict__ out1) {
  int wave = threadIdx.x >> 6, lane = threadIdx.x & 63;
  int i = blockIdx.x * 4 + wave;
  float dv = dinv[i];
  int c = cnt[i];
  float selfc = ALPHA + (1.0f - ALPHA) * dv * dv;
  float4 acc[2];
  const float* yi = y + (size_t)i * H2 + lane * 4;
  #pragma unroll
  for (int u = 0; u < 2; ++u) {
    float4 v = *(const float4*)(yi + u * 256);
    acc[u].x = selfc * v.x; acc[u].y = selfc * v.y;
    acc[u].z = selfc * v.z; acc[u].w = selfc * v.w;
  }
  for (int e = 0; e < c; ++e) {
    int j   = adjI[i * CAP + e];
    float w = adjW[i * CAP + e];
    float coef = (1.0f - ALPHA) * dv * (w * dinv[j]);
    const float* yj = y + (size_t)j * H2 + lane * 4;
    #pragma unroll
    for (int u = 0; u < 2; ++u) {
      float4 v = *(const float4*)(yj + u * 256);
      acc[u].x += coef * v.x; acc[u].y += coef * v.y;
      acc[u].z += coef * v.z; acc[u].w += coef * v.w;
    }
  }
  float* ho = out1 + (size_t)i * H2 + lane * 4;
  #pragma unroll
  for (int u = 0; u < 2; ++u) {
    float4 bb = *(const float4*)(b1 + lane * 4 + u * 256);
    float4 o;
    o.x = tanhf(acc[u].x + bb.x); o.y = tanhf(acc[u].y + bb.y);
    o.z = tanhf(acc[u].z + bb.z); o.w = tanhf(acc[u].w + bb.w);
    *(float4*)(ho + u * 256) = o;
  }
}

// ---------------- SSG propagation: h = alpha*x + (1-alpha)*A_hat x --------------
template <int HH>
__global__ void prop_kernel(const float* __restrict__ x, const int* __restrict__ adjI,
    const float* __restrict__ adjW, const int* __restrict__ cnt,
    const float* __restrict__ dinv, float* __restrict__ h) {
  constexpr int U = HH / 256;
  int wave = threadIdx.x >> 6, lane = threadIdx.x & 63;
  int i = blockIdx.x * 4 + wave;
  float dv = dinv[i];
  int c = cnt[i];
  float selfc = ALPHA + (1.0f - ALPHA) * dv * dv;
  float4 acc[U];
  const float* xi = x + (size_t)i * HH + lane * 4;
  #pragma unroll
  for (int u = 0; u < U; ++u) {
    float4 v = *(const float4*)(xi + u * 256);
    acc[u].x = selfc * v.x; acc[u].y = selfc * v.y;
    acc[u].z = selfc * v.z; acc[u].w = selfc * v.w;
  }
  for (int e = 0; e < c; ++e) {
    int j   = adjI[i * CAP + e];
    float w = adjW[i * CAP + e];
    float coef = (1.0f - ALPHA) * dv * (w * dinv[j]);
    const float* xj = x + (size_t)j * HH + lane * 4;
    #pragma unroll
    for (int u = 0; u < U; ++u) {
      float4 v = *(const float4*)(xj + u * 256);
      acc[u].x += coef * v.x; acc[u].y += coef * v.y;
      acc[u].z += coef * v.z; acc[u].w += coef * v.w;
    }
  }
  float* ho = h + (size_t)i * HH + lane * 4;
  #pragma unroll
  for (int u = 0; u < U; ++u) *(float4*)(ho + u * 256) = acc[u];
}

// ---- split fp32 -> (hi, lo) bf16 (truncation; a - hi is exact in fp32) ---------
__device__ __forceinline__ void bf16split(float a, unsigned short& hi, unsigned short& lo) {
  unsigned u = __float_as_uint(a);
  hi = (unsigned short)(u >> 16);
  float fh = __uint_as_float(u & 0xFFFF0000u);
  float fl = a - fh;
  lo = (unsigned short)(__float_as_uint(fl) >> 16);
}

// ---- MFMA split-bf16 GEMM + bias + tanh (R15, proven) --------------------------
__global__ __launch_bounds__(256) void mgemm_tanh_kernel(const float* __restrict__ A,
    const float* __restrict__ W, const float* __restrict__ bias, float* __restrict__ C) {
  __shared__ unsigned short Ahi[128][40], Alo[128][40];   // [row][k]
  __shared__ unsigned short Bhi[128][40], Blo[128][40];   // [col][k] (W transposed)
  const int m0 = blockIdx.x * 128, n0 = blockIdx.y * 128;
  const int t = threadIdx.x;
  const int w = t >> 6, lane = t & 63;
  const int lrow = lane & 15, lk = (lane >> 4) * 8;
  f32x4 acc[2][8];
  #pragma unroll
  for (int mt = 0; mt < 2; ++mt)
    #pragma unroll
    for (int nt = 0; nt < 8; ++nt) acc[mt][nt] = (f32x4){0.f, 0.f, 0.f, 0.f};

  const int arow = t >> 1, akq = (t & 1) * 16;            // A staging coords
  const int wr = t & 31, wc4 = (t >> 5) * 16;             // W staging coords

  for (int kc = 0; kc < H2; kc += 32) {
    {
      const float* src = A + (size_t)(m0 + arow) * H2 + kc + akq;
      unsigned short h[16], l[16];
      #pragma unroll
      for (int i = 0; i < 16; i += 4) {
        float4 v = *(const float4*)(src + i);
        bf16split(v.x, h[i], l[i]);     bf16split(v.y, h[i+1], l[i+1]);
        bf16split(v.z, h[i+2], l[i+2]); bf16split(v.w, h[i+3], l[i+3]);
      }
      short8 ph0 = {(short)h[0],(short)h[1],(short)h[2],(short)h[3],
                    (short)h[4],(short)h[5],(short)h[6],(short)h[7]};
      short8 ph1 = {(short)h[8],(short)h[9],(short)h[10],(short)h[11],
                    (short)h[12],(short)h[13],(short)h[14],(short)h[15]};
      short8 pl0 = {(short)l[0],(short)l[1],(short)l[2],(short)l[3],
                    (short)l[4],(short)l[5],(short)l[6],(short)l[7]};
      short8 pl1 = {(short)l[8],(short)l[9],(short)l[10],(short)l[11],
                    (short)l[12],(short)l[13],(short)l[14],(short)l[15]};
      *(short8*)&Ahi[arow][akq]     = ph0;
      *(short8*)&Ahi[arow][akq + 8] = ph1;
      *(short8*)&Alo[arow][akq]     = pl0;
      *(short8*)&Alo[arow][akq + 8] = pl1;
    }
    {
      const float* wsrc = W + (size_t)(kc + wr) * H2 + n0 + wc4;
      #pragma unroll
      for (int i = 0; i < 16; i += 4) {
        float4 v = *(const float4*)(wsrc + i);
        unsigned short h0,h1,h2,h3,l0,l1,l2,l3;
        bf16split(v.x, h0, l0); bf16split(v.y, h1, l1);
        bf16split(v.z, h2, l2); bf16split(v.w, h3, l3);
        Bhi[wc4+i+0][wr] = h0; Bhi[wc4+i+1][wr] = h1;
        Bhi[wc4+i+2][wr] = h2; Bhi[wc4+i+3][wr] = h3;
        Blo[wc4+i+0][wr] = l0; Blo[wc4+i+1][wr] = l1;
        Blo[wc4+i+2][wr] = l2; Blo[wc4+i+3][wr] = l3;
      }
    }
    __syncthreads();
    const int r0 = w * 32 + lrow;
    short8 a0h = *(const short8*)&Ahi[r0][lk];
    short8 a0l = *(const short8*)&Alo[r0][lk];
    short8 a1h = *(const short8*)&Ahi[r0 + 16][lk];
    short8 a1l = *(const short8*)&Alo[r0 + 16][lk];
    #pragma unroll
    for (int nt = 0; nt < 8; ++nt) {
      short8 bh = *(const short8*)&Bhi[nt * 16 + lrow][lk];
      short8 bl = *(const short8*)&Blo[nt * 16 + lrow][lk];
      acc[0][nt] = __builtin_amdgcn_mfma_f32_16x16x32_bf16(a0h, bh, acc[0][nt], 0, 0, 0);
      acc[0][nt] = __builtin_amdgcn_mfma_f32_16x16x32_bf16(a0l, bh, acc[0][nt], 0, 0, 0);
      acc[0][nt] = __builtin_amdgcn_mfma_f32_16x16x32_bf16(a0h, bl, acc[0][nt], 0, 0, 0);
      acc[1][nt] = __builtin_amdgcn_mfma_f32_16x16x32_bf16(a1h, bh, acc[1][nt], 0, 0, 0);
      acc[1][nt] = __builtin_amdgcn_mfma_f32_16x16x32_bf16(a1l, bh, acc[1][nt], 0, 0, 0);
      acc[1][nt] = __builtin_amdgcn_mfma_f32_16x16x32_bf16(a1h, bl, acc[1][nt], 0, 0, 0);
    }
    __syncthreads();
  }
  #pragma unroll
  for (int mt = 0; mt < 2; ++mt) {
    #pragma unroll
    for (int nt = 0; nt < 8; ++nt) {
      int col = n0 + nt * 16 + lrow;
      float bcol = bias[col];
      #pragma unroll
      for (int i = 0; i < 4; ++i) {
        int row = m0 + w * 32 + mt * 16 + (lane >> 4) * 4 + i;
        C[(size_t)row * H2 + col] = tanhf(acc[mt][nt][i] + bcol);
      }
    }
  }
}

// ---------------- mean pool over N nodes per graph ------------------------------
__global__ void pool_kernel(const float* __restrict__ x, float* __restrict__ pooled) {
  int b = blockIdx.x;
  int c = blockIdx.y * 256 + threadIdx.x;
  const float* xb = x + ((size_t)b << 10) * H2 + c;
  float s = 0.0f;
  for (int i = 0; i < N; ++i) s += xb[(size_t)i * H2];
  pooled[b * H2 + c] = s * (1.0f / N);
}

// ---------------- dense head: tanh(pooled@Wd+bd) @ Wo + bo ----------------------
__global__ void head_kernel(const float* __restrict__ pooled, const float* __restrict__ Wd,
    const float* __restrict__ bd, const float* __restrict__ Wo, const float* __restrict__ bo,
    float* __restrict__ out) {
  __shared__ float sp[512], sh[256];
  int b = blockIdx.x, t = threadIdx.x;
  sp[t] = pooled[b * H2 + t];
  sp[t + 256] = pooled[b * H2 + t + 256];
  __syncthreads();
  float acc = bd[t];
  for (int c2 = 0; c2 < 512; ++c2) acc += sp[c2] * Wd[c2 * 256 + t];
  sh[t] = tanhf(acc);
  __syncthreads();
  if (t < 8) {
    float o = bo[t];
    for (int j = 0; j < 256; ++j) o += sh[j] * Wo[j * 8 + t];
    out[b * 8 + t] = o;
  }
}

}  // namespace

extern "C" void kernel_launch(void* const* d_in, const int* in_sizes, int n_in,
                              void* d_out, int out_size, void* d_ws, size_t ws_size,
                              hipStream_t stream) {
  const float* feat = (const float*)d_in[0];
  const float* W1 = (const float*)d_in[1];
  const float* b1 = (const float*)d_in[2];
  const float* W2 = (const float*)d_in[3];
  const float* b2 = (const float*)d_in[4];
  const float* W3 = (const float*)d_in[5];
  const float* b3 = (const float*)d_in[6];
  const float* Wd = (const float*)d_in[7];
  const float* bd = (const float*)d_in[8];
  const float* Wo = (const float*)d_in[9];
  const float* bo = (const float*)d_in[10];
  float* out = (float*)d_out;
  char* ws = (char*)d_ws;

  float* dist = (float*)(ws);
  float* out1 = (float*)(ws);
  float* x2   = (float*)(ws + ((size_t)32 << 20));
  float* x3   = (float*)(ws);
  float* ybuf = (float*)(ws + ((size_t)64 << 20));
  float* hbuf = (float*)(ws + ((size_t)64 << 20));
  char* misc  = ws + ((size_t)96 << 20);
  int*   ep     = (int*)(misc);
  int*   ev     = (int*)(misc + 65536);
  float* ewt    = (float*)(misc + 131072);
  int*   cnt    = (int*)(misc + 196608);
  float* dinv   = (float*)(misc + 262144);
  int*   adjI   = (int*)(misc + 327680);
  float* adjW   = (float*)(misc + 327680 + 2097152);
  float* n2     = (float*)(misc + 327680 + 2 * 2097152);
  float* pooled = (float*)(misc + 327680 + 2 * 2097152 + 65536);

  n2_kernel<<<NT / 4, 256, 0, stream>>>(feat, n2);
  dist_kernel<<<dim3(36, 1, 16), 256, 0, stream>>>(feat, n2, dist);
  prim_gemm1_kernel<<<B + (NT / 128) * 4, 256, 0, stream>>>(
      dist, feat, W1, ep, ev, ewt, ybuf);
  adj_kernel<<<NT / 256, 256, 0, stream>>>(ep, ev, ewt, adjI, adjW, cnt, dinv);

  finish1_kernel<<<NT / 4, 256, 0, stream>>>(ybuf, adjI, adjW, cnt, dinv, b1, out1);
  prop_kernel<512><<<NT / 4, 256, 0, stream>>>(out1, adjI, adjW, cnt, dinv, hbuf);
  mgemm_tanh_kernel<<<dim3(NT / 128, 4), 256, 0, stream>>>(hbuf, W2, b2, x2);
  prop_kernel<512><<<NT / 4, 256, 0, stream>>>(x2, adjI, adjW, cnt, dinv, hbuf);
  mgemm_tanh_kernel<<<dim3(NT / 128, 4), 256, 0, stream>>>(hbuf, W3, b3, x3);

  pool_kernel<<<dim3(B, H2 / 256), 256, 0, stream>>>(x3, pooled);
  head_kernel<<<B, 256, 0, stream>>>(pooled, Wd, bd, Wo, bo, out);
}

// Round 18
// 1115.353 us; speedup vs baseline: 1.0500x; 1.0094x over previous
//
#include <hip/hip_runtime.h>
#include <math.h>

namespace {

constexpr float ALPHA = 0.3f;
constexpr int B  = 16;
constexpr int N  = 1024;
constexpr int H  = 256;
constexpr int H2 = 512;
constexpr int NT = B * N;        // 16384 total nodes
constexpr int NE = N - 1;        // 1023 MST edges per batch
constexpr int CAP = 32;          // adjacency capacity per node (MST degree << 32)

__device__ __forceinline__ unsigned umin32(unsigned a, unsigned b) { return a < b ? a : b; }

typedef __attribute__((ext_vector_type(8))) short short8;
typedef __attribute__((ext_vector_type(4))) float f32x4;

// ---------------- row squared-norms: n2[row] = sum_k x[row][k]^2 ----------------
__global__ void n2_kernel(const float* __restrict__ x, float* __restrict__ n2) {
  int wave = threadIdx.x >> 6, lane = threadIdx.x & 63;
  int row  = blockIdx.x * 4 + wave;
  float4 v = *(const float4*)(x + (size_t)row * H + lane * 4);
  float s  = v.x * v.x + v.y * v.y + v.z * v.z + v.w * v.w;
  #pragma unroll
  for (int off = 32; off; off >>= 1) s += __shfl_xor(s, off);
  if (lane == 0) n2[row] = s;
}

// ------ distance matrix, symmetric upper-tri tiles; mirror via LDS transpose ----
// (R16/R17, proven; bit-exact values)
__global__ __launch_bounds__(256) void dist_kernel(const float* __restrict__ x,
    const float* __restrict__ n2, float* __restrict__ dist) {
  __shared__ float sh[128][136];
  const int bb = blockIdx.z;
  int idx = blockIdx.x, ti = 0;
  while (idx >= 8 - ti) { idx -= 8 - ti; ++ti; }
  const int tj = ti + idx;
  const int i0 = ti * 128, j0 = tj * 128;
  const int t = threadIdx.x, tx = t & 15, ty = t >> 4;
  const float* xb = x + (size_t)bb * N * H;
  float acc[8][8] = {};
  for (int kc = 0; kc < H; kc += 16) {
    #pragma unroll
    for (int u = 0; u < 2; ++u) {
      int q = t + u * 256;
      int row = q >> 2, kf = (q & 3) * 4;
      float4 a = *(const float4*)(xb + (size_t)(i0 + row) * H + kc + kf);
      sh[kf + 0][row] = a.x; sh[kf + 1][row] = a.y;
      sh[kf + 2][row] = a.z; sh[kf + 3][row] = a.w;
      float4 bv = *(const float4*)(xb + (size_t)(j0 + row) * H + kc + kf);
      sh[16 + kf + 0][row] = bv.x; sh[16 + kf + 1][row] = bv.y;
      sh[16 + kf + 2][row] = bv.z; sh[16 + kf + 3][row] = bv.w;
    }
    __syncthreads();
    #pragma unroll
    for (int kk = 0; kk < 16; ++kk) {
      float4 a0 = *(const float4*)&sh[kk][ty * 4];
      float4 a1 = *(const float4*)&sh[kk][64 + ty * 4];
      float4 b0 = *(const float4*)&sh[16 + kk][tx * 4];
      float4 b1 = *(const float4*)&sh[16 + kk][64 + tx * 4];
      float ar[8] = {a0.x,a0.y,a0.z,a0.w,a1.x,a1.y,a1.z,a1.w};
      float br[8] = {b0.x,b0.y,b0.z,b0.w,b1.x,b1.y,b1.z,b1.w};
      #pragma unroll
      for (int r = 0; r < 8; ++r)
        #pragma unroll
        for (int c = 0; c < 8; ++c) acc[r][c] += ar[r] * br[c];
    }
    __syncthreads();
  }
  float n2i[8], n2j[8];
  #pragma unroll
  for (int r = 0; r < 8; ++r)
    n2i[r] = n2[bb * N + i0 + (r < 4 ? ty * 4 + r : 64 + ty * 4 + r - 4)];
  #pragma unroll
  for (int c = 0; c < 8; ++c)
    n2j[c] = n2[bb * N + j0 + (c < 4 ? tx * 4 + c : 64 + tx * 4 + c - 4)];
  const bool mirror = (ti != tj);
  float* distb = dist + (size_t)bb * N * N;
  #pragma unroll
  for (int r = 0; r < 8; ++r) {
    int rl = (r < 4 ? ty * 4 + r : 64 + ty * 4 + r - 4);
    float o[8];
    #pragma unroll
    for (int c = 0; c < 8; ++c) {
      float d2 = (n2i[r] + n2j[c]) - 2.0f * acc[r][c];
      o[c] = sqrtf(fmaxf(d2, 0.0f));
    }
    float* dst = distb + (size_t)(i0 + rl) * N + j0;
    *(float4*)(dst + tx * 4)      = make_float4(o[0], o[1], o[2], o[3]);
    *(float4*)(dst + 64 + tx * 4) = make_float4(o[4], o[5], o[6], o[7]);
    if (mirror) {                                   // stash for transpose
      *(float4*)&sh[rl][tx * 4]      = make_float4(o[0], o[1], o[2], o[3]);
      *(float4*)&sh[rl][64 + tx * 4] = make_float4(o[4], o[5], o[6], o[7]);
    }
  }
  if (mirror) {
    __syncthreads();                                // o-tile fully in sh
    const int q = t >> 1, half = (t & 1) * 64;      // transposed row q, half of cols
    float* gdst = distb + (size_t)(j0 + q) * N + i0 + half;
    #pragma unroll
    for (int s = 0; s < 64; s += 4) {
      float4 v;
      v.x = sh[half + s + 0][q];
      v.y = sh[half + s + 1][q];
      v.z = sh[half + s + 2][q];
      v.w = sh[half + s + 3][q];
      *(float4*)(gdst + s) = v;
    }
  }
}

// ---------------- Prim helpers -----------------------------------------------------
__device__ __forceinline__ unsigned wave_min_u32(unsigned x) {
  unsigned t;
  t = (unsigned)__builtin_amdgcn_update_dpp((int)x, (int)x, 0x111, 0xf, 0xf, false); x = umin32(x, t);
  t = (unsigned)__builtin_amdgcn_update_dpp((int)x, (int)x, 0x112, 0xf, 0xf, false); x = umin32(x, t);
  t = (unsigned)__builtin_amdgcn_update_dpp((int)x, (int)x, 0x114, 0xf, 0xf, false); x = umin32(x, t);
  t = (unsigned)__builtin_amdgcn_update_dpp((int)x, (int)x, 0x118, 0xf, 0xf, false); x = umin32(x, t);
  x = umin32(x, (unsigned)__shfl_xor((int)x, 16));
  x = umin32(x, (unsigned)__shfl_xor((int)x, 32));
  return (unsigned)__builtin_amdgcn_readlane((int)x, 63);
}

struct Sel2 { unsigned w; int j; };

// Parity-buffered block argmin: ONE barrier per call. Readers of smin[pb] (this
// call) are separated from the next write of smin[pb] (two calls later) by the
// next call's barrier -- every thread passes it after this call's reads and
// before any pb-rewrite. Selection math identical to R8 (bit-exact tree).
__device__ __forceinline__ Sel2 block_select(unsigned mw0, unsigned mw1,
    unsigned mw2, unsigned mw3, int wid, int lane,
    unsigned long long (*smin)[4], int pb) {
  unsigned lm = umin32(umin32(mw0, mw1), umin32(mw2, mw3));
  unsigned wm = wave_min_u32(lm);
  unsigned mb = (mw0 == wm ? 1u : 0u) | (mw1 == wm ? 2u : 0u) |
                (mw2 == wm ? 4u : 0u) | (mw3 == wm ? 8u : 0u);
  unsigned long long bal = __ballot(mb != 0);
  int fl = __ffsll(bal) - 1;                         // lowest matching lane
  int slot = __ffs((unsigned)__builtin_amdgcn_readlane((int)mb, fl)) - 1;
  int widx = (wid << 8) | (fl << 2) | slot;          // lowest node id in wave
  if (lane == 0)
    smin[pb][wid] = ((unsigned long long)wm << 32) | (unsigned)widx;
  __syncthreads();                                   // writes visible
  unsigned long long k0 = smin[pb][0], k1 = smin[pb][1];
  unsigned long long k2 = smin[pb][2], k3 = smin[pb][3];
  unsigned long long ka = k0 < k1 ? k0 : k1;
  unsigned long long kb = k2 < k3 ? k2 : k3;
  unsigned long long kk = ka < kb ? ka : kb;
  Sel2 r; r.w = (unsigned)(kk >> 32); r.j = (int)(unsigned)(kk & 0xFFFFFFFFu);
  return r;
}

// ------- merged: blocks 0..15 = Prim MST; 16.. = y = feat @ W1 ------------------
__global__ __launch_bounds__(256) void prim_gemm1_kernel(
    const float* __restrict__ dist, const float* __restrict__ feat,
    const float* __restrict__ W1, int* __restrict__ ep, int* __restrict__ ev,
    float* __restrict__ ewt, float* __restrict__ y) {
  __shared__ unsigned long long smin[2][4];
  __shared__ int epv[NE];
  __shared__ int evv[NE];
  __shared__ float ews[NE];
  __shared__ float As[16][132], Bs[16][132];
  if (blockIdx.x < B) {
    // ==================== Prim path (R13 logic + parity select) ====================
    const int b = blockIdx.x;
    const int tid = threadIdx.x, wid = tid >> 6, lane = tid & 63;
    const float* Db = dist + (size_t)b * N * N;
    const int jbase = tid * 4;                        // this thread's 4 nodes

    unsigned d0, d1, d2, d3;
    {
      float4 v = *(const float4*)(Db + jbase);        // row 0
      d0 = __float_as_uint(v.x); d1 = __float_as_uint(v.y);
      d2 = __float_as_uint(v.z); d3 = __float_as_uint(v.w);
    }
    unsigned mw0 = d0, mw1 = d1, mw2 = d2, mw3 = d3;
    unsigned rm0 = 0, rm1 = 0, rm2 = 0, rm3 = 0;
    int pa0 = 0, pa1 = 0, pa2 = 0, pa3 = 0;
    if (tid == 0) { rm0 = ~0u; mw0 = ~0u; }           // node 0 in tree

    Sel2 s0 = block_select(mw0, mw1, mw2, mw3, wid, lane, smin, 0);
    int cj = s0.j;
    if ((cj >> 2) == tid) {
      int sl = cj & 3;
      int pv = pa0; if (sl == 1) pv = pa1; if (sl == 2) pv = pa2; if (sl == 3) pv = pa3;
      epv[0] = pv; evv[0] = cj; ews[0] = __uint_as_float(s0.w);
      if (sl == 0) { rm0 = ~0u; mw0 = ~0u; }
      if (sl == 1) { rm1 = ~0u; mw1 = ~0u; }
      if (sl == 2) { rm2 = ~0u; mw2 = ~0u; }
      if (sl == 3) { rm3 = ~0u; mw3 = ~0u; }
    }
    float4 xq = *(const float4*)(Db + (size_t)cj * N + jbase);

    for (int k = 1; k < NE; ++k) {
      unsigned r0 = __float_as_uint(xq.x), r1 = __float_as_uint(xq.y);
      unsigned r2 = __float_as_uint(xq.z), r3 = __float_as_uint(xq.w);
      unsigned q0 = r0 | rm0, q1 = r1 | rm1, q2 = r2 | rm2, q3 = r3 | rm3;
      mw0 = umin32(mw0, q0); mw1 = umin32(mw1, q1);
      mw2 = umin32(mw2, q2); mw3 = umin32(mw3, q3);
      Sel2 se = block_select(mw0, mw1, mw2, mw3, wid, lane, smin, k & 1);
      const int nj = se.j;
      float4 nxt = *(const float4*)(Db + (size_t)nj * N + jbase);
      if (r0 < d0) { pa0 = cj; d0 = r0; }             // strict <, matches reference
      if (r1 < d1) { pa1 = cj; d1 = r1; }
      if (r2 < d2) { pa2 = cj; d2 = r2; }
      if (r3 < d3) { pa3 = cj; d3 = r3; }
      if ((nj >> 2) == tid) {                         // owner: emit + mask
        int sl = nj & 3;
        int pv = pa0; if (sl == 1) pv = pa1; if (sl == 2) pv = pa2; if (sl == 3) pv = pa3;
        epv[k] = pv; evv[k] = nj; ews[k] = __uint_as_float(se.w);
        if (sl == 0) { rm0 = ~0u; mw0 = ~0u; }
        if (sl == 1) { rm1 = ~0u; mw1 = ~0u; }
        if (sl == 2) { rm2 = ~0u; mw2 = ~0u; }
        if (sl == 3) { rm3 = ~0u; mw3 = ~0u; }
      }
      cj = nj; xq = nxt;
    }

    __syncthreads();                                  // epv/evv/ews visible
    for (int e = tid; e < NE; e += 256) {
      ep[b * NE + e]  = epv[e];
      ev[b * NE + e]  = evv[e];
      ewt[b * NE + e] = ews[e];
    }
  } else {
    // ==================== gemm1 path: y = feat @ W1 (raw, K=256) ==================
    const int gb = blockIdx.x - B;
    const int m0 = (gb >> 2) * 128, n0 = (gb & 3) * 128;
    const int t = threadIdx.x, tx = t & 15, ty = t >> 4;
    float acc[8][8] = {};
    for (int kc = 0; kc < H; kc += 16) {
      #pragma unroll
      for (int u = 0; u < 2; ++u) {
        int q = t + u * 256;
        int row = q >> 2, kf = (q & 3) * 4;
        float4 a = *(const float4*)(feat + (size_t)(m0 + row) * H + kc + kf);
        As[kf + 0][row] = a.x; As[kf + 1][row] = a.y;
        As[kf + 2][row] = a.z; As[kf + 3][row] = a.w;
        int rowB = q >> 5, cf = (q & 31) * 4;
        *(float4*)&Bs[rowB][cf] = *(const float4*)(W1 + (size_t)(kc + rowB) * H2 + n0 + cf);
      }
      __syncthreads();
      #pragma unroll
      for (int kk = 0; kk < 16; ++kk) {
        float4 a0 = *(const float4*)&As[kk][ty * 4];
        float4 a1 = *(const float4*)&As[kk][64 + ty * 4];
        float4 b0 = *(const float4*)&Bs[kk][tx * 4];
        float4 b1 = *(const float4*)&Bs[kk][64 + tx * 4];
        float ar[8] = {a0.x,a0.y,a0.z,a0.w,a1.x,a1.y,a1.z,a1.w};
        float br[8] = {b0.x,b0.y,b0.z,b0.w,b1.x,b1.y,b1.z,b1.w};
        #pragma unroll
        for (int r = 0; r < 8; ++r)
          #pragma unroll
          for (int c = 0; c < 8; ++c) acc[r][c] += ar[r] * br[c];
      }
      __syncthreads();
    }
    #pragma unroll
    for (int r = 0; r < 8; ++r) {
      int m = m0 + (r < 4 ? ty * 4 + r : 64 + ty * 4 + r - 4);
      float* dst = y + (size_t)m * H2 + n0;
      *(float4*)(dst + tx * 4)      = make_float4(acc[r][0], acc[r][1], acc[r][2], acc[r][3]);
      *(float4*)(dst + 64 + tx * 4) = make_float4(acc[r][4], acc[r][5], acc[r][6], acc[r][7]);
    }
  }
}

// ---------------- adjacency + deg^-1/2 (R15, proven; 64-block parallel) ---------
__global__ void adj_kernel(const int* __restrict__ ep, const int* __restrict__ ev,
    const float* __restrict__ ewt, int* __restrict__ adjI, float* __restrict__ adjW,
    int* __restrict__ cnt, float* __restrict__ dinv) {
  int i = blockIdx.x * 256 + threadIdx.x;
  int b = i >> 10, loc = i & 1023;
  const int* epb = ep + b * NE;
  const int* evb = ev + b * NE;
  const float* ewb = ewt + b * NE;
  int c = 0; float wsum = 0.0f;
  for (int k = 0; k < NE; ++k) {
    int p = epb[k], v = evb[k];
    if (p == loc || v == loc) {
      float w = ewb[k];
      wsum += w;
      int nb = (p == loc) ? v : p;
      if (c < CAP) { adjI[i * CAP + c] = (b << 10) + nb; adjW[i * CAP + c] = w; }
      ++c;
    }
  }
  cnt[i]  = c < CAP ? c : CAP;
  dinv[i] = 1.0f / sqrtf(wsum + 1.0f);
}

// ------ finish layer 1: out1 = tanh(alpha*y + (1-alpha)*A_hat y + b1) -----------
__global__ void finish1_kernel(const float* __restrict__ y, const int* __restrict__ adjI,
    const float* __restrict__ adjW, const int* __restrict__ cnt,
    const float* __restrict__ dinv, const float* __restrict__ b1,
    float* __restrict__ out1) {
  int wave = threadIdx.x >> 6, lane = threadIdx.x & 63;
  int i = blockIdx.x * 4 + wave;
  float dv = dinv[i];
  int c = cnt[i];
  float selfc = ALPHA + (1.0f - ALPHA) * dv * dv;
  float4 acc[2];
  const float* yi = y + (size_t)i * H2 + lane * 4;
  #pragma unroll
  for (int u = 0; u < 2; ++u) {
    float4 v = *(const float4*)(yi + u * 256);
    acc[u].x = selfc * v.x; acc[u].y = selfc * v.y;
    acc[u].z = selfc * v.z; acc[u].w = selfc * v.w;
  }
  for (int e = 0; e < c; ++e) {
    int j   = adjI[i * CAP + e];
    float w = adjW[i * CAP + e];
    float coef = (1.0f - ALPHA) * dv * (w * dinv[j]);
    const float* yj = y + (size_t)j * H2 + lane * 4;
    #pragma unroll
    for (int u = 0; u < 2; ++u) {
      float4 v = *(const float4*)(yj + u * 256);
      acc[u].x += coef * v.x; acc[u].y += coef * v.y;
      acc[u].z += coef * v.z; acc[u].w += coef * v.w;
    }
  }
  float* ho = out1 + (size_t)i * H2 + lane * 4;
  #pragma unroll
  for (int u = 0; u < 2; ++u) {
    float4 bb = *(const float4*)(b1 + lane * 4 + u * 256);
    float4 o;
    o.x = tanhf(acc[u].x + bb.x); o.y = tanhf(acc[u].y + bb.y);
    o.z = tanhf(acc[u].z + bb.z); o.w = tanhf(acc[u].w + bb.w);
    *(float4*)(ho + u * 256) = o;
  }
}

// ---------------- SSG propagation: h = alpha*x + (1-alpha)*A_hat x --------------
template <int HH>
__global__ void prop_kernel(const float* __restrict__ x, const int* __restrict__ adjI,
    const float* __restrict__ adjW, const int* __restrict__ cnt,
    const float* __restrict__ dinv, float* __restrict__ h) {
  constexpr int U = HH / 256;
  int wave = threadIdx.x >> 6, lane = threadIdx.x & 63;
  int i = blockIdx.x * 4 + wave;
  float dv = dinv[i];
  int c = cnt[i];
  float selfc = ALPHA + (1.0f - ALPHA) * dv * dv;
  float4 acc[U];
  const float* xi = x + (size_t)i * HH + lane * 4;
  #pragma unroll
  for (int u = 0; u < U; ++u) {
    float4 v = *(const float4*)(xi + u * 256);
    acc[u].x = selfc * v.x; acc[u].y = selfc * v.y;
    acc[u].z = selfc * v.z; acc[u].w = selfc * v.w;
  }
  for (int e = 0; e < c; ++e) {
    int j   = adjI[i * CAP + e];
    float w = adjW[i * CAP + e];
    float coef = (1.0f - ALPHA) * dv * (w * dinv[j]);
    const float* xj = x + (size_t)j * HH + lane * 4;
    #pragma unroll
    for (int u = 0; u < U; ++u) {
      float4 v = *(const float4*)(xj + u * 256);
      acc[u].x += coef * v.x; acc[u].y += coef * v.y;
      acc[u].z += coef * v.z; acc[u].w += coef * v.w;
    }
  }
  float* ho = h + (size_t)i * HH + lane * 4;
  #pragma unroll
  for (int u = 0; u < U; ++u) *(float4*)(ho + u * 256) = acc[u];
}

// ---- split fp32 -> (hi, lo) bf16 (truncation; a - hi is exact in fp32) ---------
__device__ __forceinline__ void bf16split(float a, unsigned short& hi, unsigned short& lo) {
  unsigned u = __float_as_uint(a);
  hi = (unsigned short)(u >> 16);
  float fh = __uint_as_float(u & 0xFFFF0000u);
  float fl = a - fh;
  lo = (unsigned short)(__float_as_uint(fl) >> 16);
}

// ---- MFMA split-bf16 GEMM + bias + tanh (R15, proven) --------------------------
__global__ __launch_bounds__(256) void mgemm_tanh_kernel(const float* __restrict__ A,
    const float* __restrict__ W, const float* __restrict__ bias, float* __restrict__ C) {
  __shared__ unsigned short Ahi[128][40], Alo[128][40];   // [row][k]
  __shared__ unsigned short Bhi[128][40], Blo[128][40];   // [col][k] (W transposed)
  const int m0 = blockIdx.x * 128, n0 = blockIdx.y * 128;
  const int t = threadIdx.x;
  const int w = t >> 6, lane = t & 63;
  const int lrow = lane & 15, lk = (lane >> 4) * 8;
  f32x4 acc[2][8];
  #pragma unroll
  for (int mt = 0; mt < 2; ++mt)
    #pragma unroll
    for (int nt = 0; nt < 8; ++nt) acc[mt][nt] = (f32x4){0.f, 0.f, 0.f, 0.f};

  const int arow = t >> 1, akq = (t & 1) * 16;            // A staging coords
  const int wr = t & 31, wc4 = (t >> 5) * 16;             // W staging coords

  for (int kc = 0; kc < H2; kc += 32) {
    {
      const float* src = A + (size_t)(m0 + arow) * H2 + kc + akq;
      unsigned short h[16], l[16];
      #pragma unroll
      for (int i = 0; i < 16; i += 4) {
        float4 v = *(const float4*)(src + i);
        bf16split(v.x, h[i], l[i]);     bf16split(v.y, h[i+1], l[i+1]);
        bf16split(v.z, h[i+2], l[i+2]); bf16split(v.w, h[i+3], l[i+3]);
      }
      short8 ph0 = {(short)h[0],(short)h[1],(short)h[2],(short)h[3],
                    (short)h[4],(short)h[5],(short)h[6],(short)h[7]};
      short8 ph1 = {(short)h[8],(short)h[9],(short)h[10],(short)h[11],
                    (short)h[12],(short)h[13],(short)h[14],(short)h[15]};
      short8 pl0 = {(short)l[0],(short)l[1],(short)l[2],(short)l[3],
                    (short)l[4],(short)l[5],(short)l[6],(short)l[7]};
      short8 pl1 = {(short)l[8],(short)l[9],(short)l[10],(short)l[11],
                    (short)l[12],(short)l[13],(short)l[14],(short)l[15]};
      *(short8*)&Ahi[arow][akq]     = ph0;
      *(short8*)&Ahi[arow][akq + 8] = ph1;
      *(short8*)&Alo[arow][akq]     = pl0;
      *(short8*)&Alo[arow][akq + 8] = pl1;
    }
    {
      const float* wsrc = W + (size_t)(kc + wr) * H2 + n0 + wc4;
      #pragma unroll
      for (int i = 0; i < 16; i += 4) {
        float4 v = *(const float4*)(wsrc + i);
        unsigned short h0,h1,h2,h3,l0,l1,l2,l3;
        bf16split(v.x, h0, l0); bf16split(v.y, h1, l1);
        bf16split(v.z, h2, l2); bf16split(v.w, h3, l3);
        Bhi[wc4+i+0][wr] = h0; Bhi[wc4+i+1][wr] = h1;
        Bhi[wc4+i+2][wr] = h2; Bhi[wc4+i+3][wr] = h3;
        Blo[wc4+i+0][wr] = l0; Blo[wc4+i+1][wr] = l1;
        Blo[wc4+i+2][wr] = l2; Blo[wc4+i+3][wr] = l3;
      }
    }
    __syncthreads();
    const int r0 = w * 32 + lrow;
    short8 a0h = *(const short8*)&Ahi[r0][lk];
    short8 a0l = *(const short8*)&Alo[r0][lk];
    short8 a1h = *(const short8*)&Ahi[r0 + 16][lk];
    short8 a1l = *(const short8*)&Alo[r0 + 16][lk];
    #pragma unroll
    for (int nt = 0; nt < 8; ++nt) {
      short8 bh = *(const short8*)&Bhi[nt * 16 + lrow][lk];
      short8 bl = *(const short8*)&Blo[nt * 16 + lrow][lk];
      acc[0][nt] = __builtin_amdgcn_mfma_f32_16x16x32_bf16(a0h, bh, acc[0][nt], 0, 0, 0);
      acc[0][nt] = __builtin_amdgcn_mfma_f32_16x16x32_bf16(a0l, bh, acc[0][nt], 0, 0, 0);
      acc[0][nt] = __builtin_amdgcn_mfma_f32_16x16x32_bf16(a0h, bl, acc[0][nt], 0, 0, 0);
      acc[1][nt] = __builtin_amdgcn_mfma_f32_16x16x32_bf16(a1h, bh, acc[1][nt], 0, 0, 0);
      acc[1][nt] = __builtin_amdgcn_mfma_f32_16x16x32_bf16(a1l, bh, acc[1][nt], 0, 0, 0);
      acc[1][nt] = __builtin_amdgcn_mfma_f32_16x16x32_bf16(a1h, bl, acc[1][nt], 0, 0, 0);
    }
    __syncthreads();
  }
  #pragma unroll
  for (int mt = 0; mt < 2; ++mt) {
    #pragma unroll
    for (int nt = 0; nt < 8; ++nt) {
      int col = n0 + nt * 16 + lrow;
      float bcol = bias[col];
      #pragma unroll
      for (int i = 0; i < 4; ++i) {
        int row = m0 + w * 32 + mt * 16 + (lane >> 4) * 4 + i;
        C[(size_t)row * H2 + col] = tanhf(acc[mt][nt][i] + bcol);
      }
    }
  }
}

// ---- fused mean-pool + dense head (same summation order as before -> bit-exact)
__global__ void pool_head_kernel(const float* __restrict__ x,
    const float* __restrict__ Wd, const float* __restrict__ bd,
    const float* __restrict__ Wo, const float* __restrict__ bo,
    float* __restrict__ out) {
  __shared__ float sp[512], shh[256];
  int b = blockIdx.x, t = threadIdx.x;
  const float* xb = x + ((size_t)b << 10) * H2;
  float s0 = 0.0f, s1 = 0.0f;
  for (int i = 0; i < N; ++i) {
    s0 += xb[(size_t)i * H2 + t];
    s1 += xb[(size_t)i * H2 + t + 256];
  }
  sp[t] = s0 * (1.0f / N);
  sp[t + 256] = s1 * (1.0f / N);
  __syncthreads();
  float acc = bd[t];
  for (int c2 = 0; c2 < 512; ++c2) acc += sp[c2] * Wd[c2 * 256 + t];
  shh[t] = tanhf(acc);
  __syncthreads();
  if (t < 8) {
    float o = bo[t];
    for (int j = 0; j < 256; ++j) o += shh[j] * Wo[j * 8 + t];
    out[b * 8 + t] = o;
  }
}

}  // namespace

extern "C" void kernel_launch(void* const* d_in, const int* in_sizes, int n_in,
                              void* d_out, int out_size, void* d_ws, size_t ws_size,
                              hipStream_t stream) {
  const float* feat = (const float*)d_in[0];
  const float* W1 = (const float*)d_in[1];
  const float* b1 = (const float*)d_in[2];
  const float* W2 = (const float*)d_in[3];
  const float* b2 = (const float*)d_in[4];
  const float* W3 = (const float*)d_in[5];
  const float* b3 = (const float*)d_in[6];
  const float* Wd = (const float*)d_in[7];
  const float* bd = (const float*)d_in[8];
  const float* Wo = (const float*)d_in[9];
  const float* bo = (const float*)d_in[10];
  float* out = (float*)d_out;
  char* ws = (char*)d_ws;

  float* dist = (float*)(ws);
  float* out1 = (float*)(ws);
  float* x2   = (float*)(ws + ((size_t)32 << 20));
  float* x3   = (float*)(ws);
  float* ybuf = (float*)(ws + ((size_t)64 << 20));
  float* hbuf = (float*)(ws + ((size_t)64 << 20));
  char* misc  = ws + ((size_t)96 << 20);
  int*   ep     = (int*)(misc);
  int*   ev     = (int*)(misc + 65536);
  float* ewt    = (float*)(misc + 131072);
  int*   cnt    = (int*)(misc + 196608);
  float* dinv   = (float*)(misc + 262144);
  int*   adjI   = (int*)(misc + 327680);
  float* adjW   = (float*)(misc + 327680 + 2097152);
  float* n2     = (float*)(misc + 327680 + 2 * 2097152);

  n2_kernel<<<NT / 4, 256, 0, stream>>>(feat, n2);
  dist_kernel<<<dim3(36, 1, 16), 256, 0, stream>>>(feat, n2, dist);
  prim_gemm1_kernel<<<B + (NT / 128) * 4, 256, 0, stream>>>(
      dist, feat, W1, ep, ev, ewt, ybuf);
  adj_kernel<<<NT / 256, 256, 0, stream>>>(ep, ev, ewt, adjI, adjW, cnt, dinv);

  finish1_kernel<<<NT / 4, 256, 0, stream>>>(ybuf, adjI, adjW, cnt, dinv, b1, out1);
  prop_kernel<512><<<NT / 4, 256, 0, stream>>>(out1, adjI, adjW, cnt, dinv, hbuf);
  mgemm_tanh_kernel<<<dim3(NT / 128, 4), 256, 0, stream>>>(hbuf, W2, b2, x2);
  prop_kernel<512><<<NT / 4, 256, 0, stream>>>(x2, adjI, adjW, cnt, dinv, hbuf);
  mgemm_tanh_kernel<<<dim3(NT / 128, 4), 256, 0, stream>>>(hbuf, W3, b3, x3);

  pool_head_kernel<<<B, 256, 0, stream>>>(x3, Wd, bd, Wo, bo, out);
}

// Round 19
// 1052.337 us; speedup vs baseline: 1.1129x; 1.0599x over previous
//
#include <hip/hip_runtime.h>
#include <math.h>

namespace {

constexpr float ALPHA = 0.3f;
constexpr int B  = 16;
constexpr int N  = 1024;
constexpr int H  = 256;
constexpr int H2 = 512;
constexpr int NT = B * N;        // 16384 total nodes
constexpr int NE = N - 1;        // 1023 MST edges per batch
constexpr int CAP = 32;          // adjacency capacity per node (MST degree << 32)
constexpr int GEMM1_BLKS = (NT / 128) * 4;   // 512

__device__ __forceinline__ unsigned umin32(unsigned a, unsigned b) { return a < b ? a : b; }

typedef __attribute__((ext_vector_type(8))) short short8;
typedef __attribute__((ext_vector_type(4))) float f32x4;

// ---------------- row squared-norms + per-call flag clear -----------------------
__global__ void n2_kernel(const float* __restrict__ x, float* __restrict__ n2,
                          int* __restrict__ flags) {
  if (blockIdx.x == 0 && threadIdx.x < B) flags[threadIdx.x] = 0;  // reset each call
  int wave = threadIdx.x >> 6, lane = threadIdx.x & 63;
  int row  = blockIdx.x * 4 + wave;
  float4 v = *(const float4*)(x + (size_t)row * H + lane * 4);
  float s  = v.x * v.x + v.y * v.y + v.z * v.z + v.w * v.w;
  #pragma unroll
  for (int off = 32; off; off >>= 1) s += __shfl_xor(s, off);
  if (lane == 0) n2[row] = s;
}

// ------ distance matrix, symmetric upper-tri tiles; mirror via LDS transpose ----
__global__ __launch_bounds__(256) void dist_kernel(const float* __restrict__ x,
    const float* __restrict__ n2, float* __restrict__ dist) {
  __shared__ float sh[128][136];
  const int bb = blockIdx.z;
  int idx = blockIdx.x, ti = 0;
  while (idx >= 8 - ti) { idx -= 8 - ti; ++ti; }
  const int tj = ti + idx;
  const int i0 = ti * 128, j0 = tj * 128;
  const int t = threadIdx.x, tx = t & 15, ty = t >> 4;
  const float* xb = x + (size_t)bb * N * H;
  float acc[8][8] = {};
  for (int kc = 0; kc < H; kc += 16) {
    #pragma unroll
    for (int u = 0; u < 2; ++u) {
      int q = t + u * 256;
      int row = q >> 2, kf = (q & 3) * 4;
      float4 a = *(const float4*)(xb + (size_t)(i0 + row) * H + kc + kf);
      sh[kf + 0][row] = a.x; sh[kf + 1][row] = a.y;
      sh[kf + 2][row] = a.z; sh[kf + 3][row] = a.w;
      float4 bv = *(const float4*)(xb + (size_t)(j0 + row) * H + kc + kf);
      sh[16 + kf + 0][row] = bv.x; sh[16 + kf + 1][row] = bv.y;
      sh[16 + kf + 2][row] = bv.z; sh[16 + kf + 3][row] = bv.w;
    }
    __syncthreads();
    #pragma unroll
    for (int kk = 0; kk < 16; ++kk) {
      float4 a0 = *(const float4*)&sh[kk][ty * 4];
      float4 a1 = *(const float4*)&sh[kk][64 + ty * 4];
      float4 b0 = *(const float4*)&sh[16 + kk][tx * 4];
      float4 b1 = *(const float4*)&sh[16 + kk][64 + tx * 4];
      float ar[8] = {a0.x,a0.y,a0.z,a0.w,a1.x,a1.y,a1.z,a1.w};
      float br[8] = {b0.x,b0.y,b0.z,b0.w,b1.x,b1.y,b1.z,b1.w};
      #pragma unroll
      for (int r = 0; r < 8; ++r)
        #pragma unroll
        for (int c = 0; c < 8; ++c) acc[r][c] += ar[r] * br[c];
    }
    __syncthreads();
  }
  float n2i[8], n2j[8];
  #pragma unroll
  for (int r = 0; r < 8; ++r)
    n2i[r] = n2[bb * N + i0 + (r < 4 ? ty * 4 + r : 64 + ty * 4 + r - 4)];
  #pragma unroll
  for (int c = 0; c < 8; ++c)
    n2j[c] = n2[bb * N + j0 + (c < 4 ? tx * 4 + c : 64 + tx * 4 + c - 4)];
  const bool mirror = (ti != tj);
  float* distb = dist + (size_t)bb * N * N;
  #pragma unroll
  for (int r = 0; r < 8; ++r) {
    int rl = (r < 4 ? ty * 4 + r : 64 + ty * 4 + r - 4);
    float o[8];
    #pragma unroll
    for (int c = 0; c < 8; ++c) {
      float d2 = (n2i[r] + n2j[c]) - 2.0f * acc[r][c];
      o[c] = sqrtf(fmaxf(d2, 0.0f));
    }
    float* dst = distb + (size_t)(i0 + rl) * N + j0;
    *(float4*)(dst + tx * 4)      = make_float4(o[0], o[1], o[2], o[3]);
    *(float4*)(dst + 64 + tx * 4) = make_float4(o[4], o[5], o[6], o[7]);
    if (mirror) {                                   // stash for transpose
      *(float4*)&sh[rl][tx * 4]      = make_float4(o[0], o[1], o[2], o[3]);
      *(float4*)&sh[rl][64 + tx * 4] = make_float4(o[4], o[5], o[6], o[7]);
    }
  }
  if (mirror) {
    __syncthreads();                                // o-tile fully in sh
    const int q = t >> 1, half = (t & 1) * 64;      // transposed row q, half of cols
    float* gdst = distb + (size_t)(j0 + q) * N + i0 + half;
    #pragma unroll
    for (int s = 0; s < 64; s += 4) {
      float4 v;
      v.x = sh[half + s + 0][q];
      v.y = sh[half + s + 1][q];
      v.z = sh[half + s + 2][q];
      v.w = sh[half + s + 3][q];
      *(float4*)(gdst + s) = v;
    }
  }
}

// ---------------- Prim helpers -----------------------------------------------------
__device__ __forceinline__ unsigned wave_min_u32(unsigned x) {
  unsigned t;
  t = (unsigned)__builtin_amdgcn_update_dpp((int)x, (int)x, 0x111, 0xf, 0xf, false); x = umin32(x, t);
  t = (unsigned)__builtin_amdgcn_update_dpp((int)x, (int)x, 0x112, 0xf, 0xf, false); x = umin32(x, t);
  t = (unsigned)__builtin_amdgcn_update_dpp((int)x, (int)x, 0x114, 0xf, 0xf, false); x = umin32(x, t);
  t = (unsigned)__builtin_amdgcn_update_dpp((int)x, (int)x, 0x118, 0xf, 0xf, false); x = umin32(x, t);
  x = umin32(x, (unsigned)__shfl_xor((int)x, 16));
  x = umin32(x, (unsigned)__shfl_xor((int)x, 32));
  return (unsigned)__builtin_amdgcn_readlane((int)x, 63);
}

struct Sel2 { unsigned w; int j; };

// Parity-buffered block argmin: ONE barrier per call (R18, proven bit-exact).
__device__ __forceinline__ Sel2 block_select(unsigned mw0, unsigned mw1,
    unsigned mw2, unsigned mw3, int wid, int lane,
    unsigned long long (*smin)[4], int pb) {
  unsigned lm = umin32(umin32(mw0, mw1), umin32(mw2, mw3));
  unsigned wm = wave_min_u32(lm);
  unsigned mb = (mw0 == wm ? 1u : 0u) | (mw1 == wm ? 2u : 0u) |
                (mw2 == wm ? 4u : 0u) | (mw3 == wm ? 8u : 0u);
  unsigned long long bal = __ballot(mb != 0);
  int fl = __ffsll(bal) - 1;                         // lowest matching lane
  int slot = __ffs((unsigned)__builtin_amdgcn_readlane((int)mb, fl)) - 1;
  int widx = (wid << 8) | (fl << 2) | slot;          // lowest node id in wave
  if (lane == 0)
    smin[pb][wid] = ((unsigned long long)wm << 32) | (unsigned)widx;
  __syncthreads();                                   // writes visible
  unsigned long long k0 = smin[pb][0], k1 = smin[pb][1];
  unsigned long long k2 = smin[pb][2], k3 = smin[pb][3];
  unsigned long long ka = k0 < k1 ? k0 : k1;
  unsigned long long kb = k2 < k3 ? k2 : k3;
  unsigned long long kk = ka < kb ? ka : kb;
  Sel2 r; r.w = (unsigned)(kk >> 32); r.j = (int)(unsigned)(kk & 0xFFFFFFFFu);
  return r;
}

// ------- merged: blocks 0..15 = Prim; 16..527 = feat@W1; 528..543 = L2 warmers --
// Warmer i re-streams dist[batch i] (reads only) on XCD i%8 -- the same XCD as
// prim block i under round-robin dispatch -- keeping prim's rows L2-resident.
// Warmers poll flags[i] (set by prim i at the end; cleared each call in n2) with
// a hard pass cap, so termination is guaranteed and correctness is untouched.
__global__ __launch_bounds__(256) void prim_gemm1_kernel(
    const float* __restrict__ dist, const float* __restrict__ feat,
    const float* __restrict__ W1, int* __restrict__ ep, int* __restrict__ ev,
    float* __restrict__ ewt, float* __restrict__ y, int* __restrict__ flags) {
  __shared__ unsigned long long smin[2][4];
  __shared__ int epv[NE];
  __shared__ int evv[NE];
  __shared__ float ews[NE];
  __shared__ float As[16][132], Bs[16][132];
  if (blockIdx.x < B) {
    // ==================== Prim path (R18, byte-identical) ====================
    const int b = blockIdx.x;
    const int tid = threadIdx.x, wid = tid >> 6, lane = tid & 63;
    const float* Db = dist + (size_t)b * N * N;
    const int jbase = tid * 4;                        // this thread's 4 nodes

    unsigned d0, d1, d2, d3;
    {
      float4 v = *(const float4*)(Db + jbase);        // row 0
      d0 = __float_as_uint(v.x); d1 = __float_as_uint(v.y);
      d2 = __float_as_uint(v.z); d3 = __float_as_uint(v.w);
    }
    unsigned mw0 = d0, mw1 = d1, mw2 = d2, mw3 = d3;
    unsigned rm0 = 0, rm1 = 0, rm2 = 0, rm3 = 0;
    int pa0 = 0, pa1 = 0, pa2 = 0, pa3 = 0;
    if (tid == 0) { rm0 = ~0u; mw0 = ~0u; }           // node 0 in tree

    Sel2 s0 = block_select(mw0, mw1, mw2, mw3, wid, lane, smin, 0);
    int cj = s0.j;
    if ((cj >> 2) == tid) {
      int sl = cj & 3;
      int pv = pa0; if (sl == 1) pv = pa1; if (sl == 2) pv = pa2; if (sl == 3) pv = pa3;
      epv[0] = pv; evv[0] = cj; ews[0] = __uint_as_float(s0.w);
      if (sl == 0) { rm0 = ~0u; mw0 = ~0u; }
      if (sl == 1) { rm1 = ~0u; mw1 = ~0u; }
      if (sl == 2) { rm2 = ~0u; mw2 = ~0u; }
      if (sl == 3) { rm3 = ~0u; mw3 = ~0u; }
    }
    float4 xq = *(const float4*)(Db + (size_t)cj * N + jbase);

    for (int k = 1; k < NE; ++k) {
      unsigned r0 = __float_as_uint(xq.x), r1 = __float_as_uint(xq.y);
      unsigned r2 = __float_as_uint(xq.z), r3 = __float_as_uint(xq.w);
      unsigned q0 = r0 | rm0, q1 = r1 | rm1, q2 = r2 | rm2, q3 = r3 | rm3;
      mw0 = umin32(mw0, q0); mw1 = umin32(mw1, q1);
      mw2 = umin32(mw2, q2); mw3 = umin32(mw3, q3);
      Sel2 se = block_select(mw0, mw1, mw2, mw3, wid, lane, smin, k & 1);
      const int nj = se.j;
      float4 nxt = *(const float4*)(Db + (size_t)nj * N + jbase);
      if (r0 < d0) { pa0 = cj; d0 = r0; }             // strict <, matches reference
      if (r1 < d1) { pa1 = cj; d1 = r1; }
      if (r2 < d2) { pa2 = cj; d2 = r2; }
      if (r3 < d3) { pa3 = cj; d3 = r3; }
      if ((nj >> 2) == tid) {                         // owner: emit + mask
        int sl = nj & 3;
        int pv = pa0; if (sl == 1) pv = pa1; if (sl == 2) pv = pa2; if (sl == 3) pv = pa3;
        epv[k] = pv; evv[k] = nj; ews[k] = __uint_as_float(se.w);
        if (sl == 0) { rm0 = ~0u; mw0 = ~0u; }
        if (sl == 1) { rm1 = ~0u; mw1 = ~0u; }
        if (sl == 2) { rm2 = ~0u; mw2 = ~0u; }
        if (sl == 3) { rm3 = ~0u; mw3 = ~0u; }
      }
      cj = nj; xq = nxt;
    }

    __syncthreads();                                  // epv/evv/ews visible
    for (int e = tid; e < NE; e += 256) {
      ep[b * NE + e]  = epv[e];
      ev[b * NE + e]  = evv[e];
      ewt[b * NE + e] = ews[e];
    }
    if (tid == 0) atomicExch(&flags[b], 1);           // release warmer b
  } else if (blockIdx.x < B + GEMM1_BLKS) {
    // ==================== gemm1 path: y = feat @ W1 (raw, K=256) ==================
    const int gb = blockIdx.x - B;
    const int m0 = (gb >> 2) * 128, n0 = (gb & 3) * 128;
    const int t = threadIdx.x, tx = t & 15, ty = t >> 4;
    float acc[8][8] = {};
    for (int kc = 0; kc < H; kc += 16) {
      #pragma unroll
      for (int u = 0; u < 2; ++u) {
        int q = t + u * 256;
        int row = q >> 2, kf = (q & 3) * 4;
        float4 a = *(const float4*)(feat + (size_t)(m0 + row) * H + kc + kf);
        As[kf + 0][row] = a.x; As[kf + 1][row] = a.y;
        As[kf + 2][row] = a.z; As[kf + 3][row] = a.w;
        int rowB = q >> 5, cf = (q & 31) * 4;
        *(float4*)&Bs[rowB][cf] = *(const float4*)(W1 + (size_t)(kc + rowB) * H2 + n0 + cf);
      }
      __syncthreads();
      #pragma unroll
      for (int kk = 0; kk < 16; ++kk) {
        float4 a0 = *(const float4*)&As[kk][ty * 4];
        float4 a1 = *(const float4*)&As[kk][64 + ty * 4];
        float4 b0 = *(const float4*)&Bs[kk][tx * 4];
        float4 b1 = *(const float4*)&Bs[kk][64 + tx * 4];
        float ar[8] = {a0.x,a0.y,a0.z,a0.w,a1.x,a1.y,a1.z,a1.w};
        float br[8] = {b0.x,b0.y,b0.z,b0.w,b1.x,b1.y,b1.z,b1.w};
        #pragma unroll
        for (int r = 0; r < 8; ++r)
          #pragma unroll
          for (int c = 0; c < 8; ++c) acc[r][c] += ar[r] * br[c];
      }
      __syncthreads();
    }
    #pragma unroll
    for (int r = 0; r < 8; ++r) {
      int m = m0 + (r < 4 ? ty * 4 + r : 64 + ty * 4 + r - 4);
      float* dst = y + (size_t)m * H2 + n0;
      *(float4*)(dst + tx * 4)      = make_float4(acc[r][0], acc[r][1], acc[r][2], acc[r][3]);
      *(float4*)(dst + 64 + tx * 4) = make_float4(acc[r][4], acc[r][5], acc[r][6], acc[r][7]);
    }
  } else {
    // ==================== warmer path: keep dist[wb] hot in this XCD's L2 ========
    const int wb = blockIdx.x - (B + GEMM1_BLKS);     // 0..15; XCD (528+wb)%8 == wb%8
    const float* Dw = dist + (size_t)wb * N * N;
    volatile const int* flag = flags + wb;
    const int t = threadIdx.x;
    for (int pass = 0; pass < 16; ++pass) {           // hard cap: guaranteed exit
      if (*flag != 0) break;
      for (int off = 0; off < N * N; off += 16384) {  // 64 KB chunks
        if (*flag != 0) break;
        float s = 0.0f;
        #pragma unroll
        for (int q = 0; q < 16; ++q) {                // 16 x 256thr x 16B = 64 KB
          float4 vv = *(const float4*)(Dw + off + q * 1024 + t * 4);
          s += vv.x + vv.y + vv.z + vv.w;
        }
        asm volatile("" :: "v"(s));                   // keep loads alive, no store
      }
    }
  }
}

// ---------------- adjacency + deg^-1/2 (R15, proven; 64-block parallel) ---------
__global__ void adj_kernel(const int* __restrict__ ep, const int* __restrict__ ev,
    const float* __restrict__ ewt, int* __restrict__ adjI, float* __restrict__ adjW,
    int* __restrict__ cnt, float* __restrict__ dinv) {
  int i = blockIdx.x * 256 + threadIdx.x;
  int b = i >> 10, loc = i & 1023;
  const int* epb = ep + b * NE;
  const int* evb = ev + b * NE;
  const float* ewb = ewt + b * NE;
  int c = 0; float wsum = 0.0f;
  for (int k = 0; k < NE; ++k) {
    int p = epb[k], v = evb[k];
    if (p == loc || v == loc) {
      float w = ewb[k];
      wsum += w;
      int nb = (p == loc) ? v : p;
      if (c < CAP) { adjI[i * CAP + c] = (b << 10) + nb; adjW[i * CAP + c] = w; }
      ++c;
    }
  }
  cnt[i]  = c < CAP ? c : CAP;
  dinv[i] = 1.0f / sqrtf(wsum + 1.0f);
}

// ------ finish layer 1: out1 = tanh(alpha*y + (1-alpha)*A_hat y + b1) -----------
__global__ void finish1_kernel(const float* __restrict__ y, const int* __restrict__ adjI,
    const float* __restrict__ adjW, const int* __restrict__ cnt,
    const float* __restrict__ dinv, const float* __restrict__ b1,
    float* __restrict__ out1) {
  int wave = threadIdx.x >> 6, lane = threadIdx.x & 63;
  int i = blockIdx.x * 4 + wave;
  float dv = dinv[i];
  int c = cnt[i];
  float selfc = ALPHA + (1.0f - ALPHA) * dv * dv;
  float4 acc[2];
  const float* yi = y + (size_t)i * H2 + lane * 4;
  #pragma unroll
  for (int u = 0; u < 2; ++u) {
    float4 v = *(const float4*)(yi + u * 256);
    acc[u].x = selfc * v.x; acc[u].y = selfc * v.y;
    acc[u].z = selfc * v.z; acc[u].w = selfc * v.w;
  }
  for (int e = 0; e < c; ++e) {
    int j   = adjI[i * CAP + e];
    float w = adjW[i * CAP + e];
    float coef = (1.0f - ALPHA) * dv * (w * dinv[j]);
    const float* yj = y + (size_t)j * H2 + lane * 4;
    #pragma unroll
    for (int u = 0; u < 2; ++u) {
      float4 v = *(const float4*)(yj + u * 256);
      acc[u].x += coef * v.x; acc[u].y += coef * v.y;
      acc[u].z += coef * v.z; acc[u].w += coef * v.w;
    }
  }
  float* ho = out1 + (size_t)i * H2 + lane * 4;
  #pragma unroll
  for (int u = 0; u < 2; ++u) {
    float4 bb = *(const float4*)(b1 + lane * 4 + u * 256);
    float4 o;
    o.x = tanhf(acc[u].x + bb.x); o.y = tanhf(acc[u].y + bb.y);
    o.z = tanhf(acc[u].z + bb.z); o.w = tanhf(acc[u].w + bb.w);
    *(float4*)(ho + u * 256) = o;
  }
}

// ---------------- SSG propagation: h = alpha*x + (1-alpha)*A_hat x --------------
template <int HH>
__global__ void prop_kernel(const float* __restrict__ x, const int* __restrict__ adjI,
    const float* __restrict__ adjW, const int* __restrict__ cnt,
    const float* __restrict__ dinv, float* __restrict__ h) {
  constexpr int U = HH / 256;
  int wave = threadIdx.x >> 6, lane = threadIdx.x & 63;
  int i = blockIdx.x * 4 + wave;
  float dv = dinv[i];
  int c = cnt[i];
  float selfc = ALPHA + (1.0f - ALPHA) * dv * dv;
  float4 acc[U];
  const float* xi = x + (size_t)i * HH + lane * 4;
  #pragma unroll
  for (int u = 0; u < U; ++u) {
    float4 v = *(const float4*)(xi + u * 256);
    acc[u].x = selfc * v.x; acc[u].y = selfc * v.y;
    acc[u].z = selfc * v.z; acc[u].w = selfc * v.w;
  }
  for (int e = 0; e < c; ++e) {
    int j   = adjI[i * CAP + e];
    float w = adjW[i * CAP + e];
    float coef = (1.0f - ALPHA) * dv * (w * dinv[j]);
    const float* xj = x + (size_t)j * HH + lane * 4;
    #pragma unroll
    for (int u = 0; u < U; ++u) {
      float4 v = *(const float4*)(xj + u * 256);
      acc[u].x += coef * v.x; acc[u].y += coef * v.y;
      acc[u].z += coef * v.z; acc[u].w += coef * v.w;
    }
  }
  float* ho = h + (size_t)i * HH + lane * 4;
  #pragma unroll
  for (int u = 0; u < U; ++u) *(float4*)(ho + u * 256) = acc[u];
}

// ---- split fp32 -> (hi, lo) bf16 (truncation; a - hi is exact in fp32) ---------
__device__ __forceinline__ void bf16split(float a, unsigned short& hi, unsigned short& lo) {
  unsigned u = __float_as_uint(a);
  hi = (unsigned short)(u >> 16);
  float fh = __uint_as_float(u & 0xFFFF0000u);
  float fl = a - fh;
  lo = (unsigned short)(__float_as_uint(fl) >> 16);
}

// ---- MFMA split-bf16 GEMM + bias + tanh (R15, proven) --------------------------
__global__ __launch_bounds__(256) void mgemm_tanh_kernel(const float* __restrict__ A,
    const float* __restrict__ W, const float* __restrict__ bias, float* __restrict__ C) {
  __shared__ unsigned short Ahi[128][40], Alo[128][40];   // [row][k]
  __shared__ unsigned short Bhi[128][40], Blo[128][40];   // [col][k] (W transposed)
  const int m0 = blockIdx.x * 128, n0 = blockIdx.y * 128;
  const int t = threadIdx.x;
  const int w = t >> 6, lane = t & 63;
  const int lrow = lane & 15, lk = (lane >> 4) * 8;
  f32x4 acc[2][8];
  #pragma unroll
  for (int mt = 0; mt < 2; ++mt)
    #pragma unroll
    for (int nt = 0; nt < 8; ++nt) acc[mt][nt] = (f32x4){0.f, 0.f, 0.f, 0.f};

  const int arow = t >> 1, akq = (t & 1) * 16;            // A staging coords
  const int wr = t & 31, wc4 = (t >> 5) * 16;             // W staging coords

  for (int kc = 0; kc < H2; kc += 32) {
    {
      const float* src = A + (size_t)(m0 + arow) * H2 + kc + akq;
      unsigned short h[16], l[16];
      #pragma unroll
      for (int i = 0; i < 16; i += 4) {
        float4 v = *(const float4*)(src + i);
        bf16split(v.x, h[i], l[i]);     bf16split(v.y, h[i+1], l[i+1]);
        bf16split(v.z, h[i+2], l[i+2]); bf16split(v.w, h[i+3], l[i+3]);
      }
      short8 ph0 = {(short)h[0],(short)h[1],(short)h[2],(short)h[3],
                    (short)h[4],(short)h[5],(short)h[6],(short)h[7]};
      short8 ph1 = {(short)h[8],(short)h[9],(short)h[10],(short)h[11],
                    (short)h[12],(short)h[13],(short)h[14],(short)h[15]};
      short8 pl0 = {(short)l[0],(short)l[1],(short)l[2],(short)l[3],
                    (short)l[4],(short)l[5],(short)l[6],(short)l[7]};
      short8 pl1 = {(short)l[8],(short)l[9],(short)l[10],(short)l[11],
                    (short)l[12],(short)l[13],(short)l[14],(short)l[15]};
      *(short8*)&Ahi[arow][akq]     = ph0;
      *(short8*)&Ahi[arow][akq + 8] = ph1;
      *(short8*)&Alo[arow][akq]     = pl0;
      *(short8*)&Alo[arow][akq + 8] = pl1;
    }
    {
      const float* wsrc = W + (size_t)(kc + wr) * H2 + n0 + wc4;
      #pragma unroll
      for (int i = 0; i < 16; i += 4) {
        float4 v = *(const float4*)(wsrc + i);
        unsigned short h0,h1,h2,h3,l0,l1,l2,l3;
        bf16split(v.x, h0, l0); bf16split(v.y, h1, l1);
        bf16split(v.z, h2, l2); bf16split(v.w, h3, l3);
        Bhi[wc4+i+0][wr] = h0; Bhi[wc4+i+1][wr] = h1;
        Bhi[wc4+i+2][wr] = h2; Bhi[wc4+i+3][wr] = h3;
        Blo[wc4+i+0][wr] = l0; Blo[wc4+i+1][wr] = l1;
        Blo[wc4+i+2][wr] = l2; Blo[wc4+i+3][wr] = l3;
      }
    }
    __syncthreads();
    const int r0 = w * 32 + lrow;
    short8 a0h = *(const short8*)&Ahi[r0][lk];
    short8 a0l = *(const short8*)&Alo[r0][lk];
    short8 a1h = *(const short8*)&Ahi[r0 + 16][lk];
    short8 a1l = *(const short8*)&Alo[r0 + 16][lk];
    #pragma unroll
    for (int nt = 0; nt < 8; ++nt) {
      short8 bh = *(const short8*)&Bhi[nt * 16 + lrow][lk];
      short8 bl = *(const short8*)&Blo[nt * 16 + lrow][lk];
      acc[0][nt] = __builtin_amdgcn_mfma_f32_16x16x32_bf16(a0h, bh, acc[0][nt], 0, 0, 0);
      acc[0][nt] = __builtin_amdgcn_mfma_f32_16x16x32_bf16(a0l, bh, acc[0][nt], 0, 0, 0);
      acc[0][nt] = __builtin_amdgcn_mfma_f32_16x16x32_bf16(a0h, bl, acc[0][nt], 0, 0, 0);
      acc[1][nt] = __builtin_amdgcn_mfma_f32_16x16x32_bf16(a1h, bh, acc[1][nt], 0, 0, 0);
      acc[1][nt] = __builtin_amdgcn_mfma_f32_16x16x32_bf16(a1l, bh, acc[1][nt], 0, 0, 0);
      acc[1][nt] = __builtin_amdgcn_mfma_f32_16x16x32_bf16(a1h, bl, acc[1][nt], 0, 0, 0);
    }
    __syncthreads();
  }
  #pragma unroll
  for (int mt = 0; mt < 2; ++mt) {
    #pragma unroll
    for (int nt = 0; nt < 8; ++nt) {
      int col = n0 + nt * 16 + lrow;
      float bcol = bias[col];
      #pragma unroll
      for (int i = 0; i < 4; ++i) {
        int row = m0 + w * 32 + mt * 16 + (lane >> 4) * 4 + i;
        C[(size_t)row * H2 + col] = tanhf(acc[mt][nt][i] + bcol);
      }
    }
  }
}

// ---- fused mean-pool + dense head (R18, proven bit-exact) ----------------------
__global__ void pool_head_kernel(const float* __restrict__ x,
    const float* __restrict__ Wd, const float* __restrict__ bd,
    const float* __restrict__ Wo, const float* __restrict__ bo,
    float* __restrict__ out) {
  __shared__ float sp[512], shh[256];
  int b = blockIdx.x, t = threadIdx.x;
  const float* xb = x + ((size_t)b << 10) * H2;
  float s0 = 0.0f, s1 = 0.0f;
  for (int i = 0; i < N; ++i) {
    s0 += xb[(size_t)i * H2 + t];
    s1 += xb[(size_t)i * H2 + t + 256];
  }
  sp[t] = s0 * (1.0f / N);
  sp[t + 256] = s1 * (1.0f / N);
  __syncthreads();
  float acc = bd[t];
  for (int c2 = 0; c2 < 512; ++c2) acc += sp[c2] * Wd[c2 * 256 + t];
  shh[t] = tanhf(acc);
  __syncthreads();
  if (t < 8) {
    float o = bo[t];
    for (int j = 0; j < 256; ++j) o += shh[j] * Wo[j * 8 + t];
    out[b * 8 + t] = o;
  }
}

}  // namespace

extern "C" void kernel_launch(void* const* d_in, const int* in_sizes, int n_in,
                              void* d_out, int out_size, void* d_ws, size_t ws_size,
                              hipStream_t stream) {
  const float* feat = (const float*)d_in[0];
  const float* W1 = (const float*)d_in[1];
  const float* b1 = (const float*)d_in[2];
  const float* W2 = (const float*)d_in[3];
  const float* b2 = (const float*)d_in[4];
  const float* W3 = (const float*)d_in[5];
  const float* b3 = (const float*)d_in[6];
  const float* Wd = (const float*)d_in[7];
  const float* bd = (const float*)d_in[8];
  const float* Wo = (const float*)d_in[9];
  const float* bo = (const float*)d_in[10];
  float* out = (float*)d_out;
  char* ws = (char*)d_ws;

  float* dist = (float*)(ws);
  float* out1 = (float*)(ws);
  float* x2   = (float*)(ws + ((size_t)32 << 20));
  float* x3   = (float*)(ws);
  float* ybuf = (float*)(ws + ((size_t)64 << 20));
  float* hbuf = (float*)(ws + ((size_t)64 << 20));
  char* misc  = ws + ((size_t)96 << 20);
  int*   ep     = (int*)(misc);
  int*   ev     = (int*)(misc + 65536);
  float* ewt    = (float*)(misc + 131072);
  int*   cnt    = (int*)(misc + 196608);
  float* dinv   = (float*)(misc + 262144);
  int*   adjI   = (int*)(misc + 327680);
  float* adjW   = (float*)(misc + 327680 + 2097152);
  float* n2     = (float*)(misc + 327680 + 2 * 2097152);
  int*   flags  = (int*)(misc + 327680 + 2 * 2097152 + 65536);

  n2_kernel<<<NT / 4, 256, 0, stream>>>(feat, n2, flags);
  dist_kernel<<<dim3(36, 1, 16), 256, 0, stream>>>(feat, n2, dist);
  prim_gemm1_kernel<<<B + GEMM1_BLKS + B, 256, 0, stream>>>(
      dist, feat, W1, ep, ev, ewt, ybuf, flags);
  adj_kernel<<<NT / 256, 256, 0, stream>>>(ep, ev, ewt, adjI, adjW, cnt, dinv);

  finish1_kernel<<<NT / 4, 256, 0, stream>>>(ybuf, adjI, adjW, cnt, dinv, b1, out1);
  prop_kernel<512><<<NT / 4, 256, 0, stream>>>(out1, adjI, adjW, cnt, dinv, hbuf);
  mgemm_tanh_kernel<<<dim3(NT / 128, 4), 256, 0, stream>>>(hbuf, W2, b2, x2);
  prop_kernel<512><<<NT / 4, 256, 0, stream>>>(x2, adjI, adjW, cnt, dinv, hbuf);
  mgemm_tanh_kernel<<<dim3(NT / 128, 4), 256, 0, stream>>>(hbuf, W3, b3, x3);

  pool_head_kernel<<<B, 256, 0, stream>>>(x3, Wd, bd, Wo, bo, out);
}

// Round 20
// 1048.628 us; speedup vs baseline: 1.1169x; 1.0035x over previous
//
#include <hip/hip_runtime.h>
#include <math.h>

namespace {

constexpr float ALPHA = 0.3f;
constexpr int B  = 16;
constexpr int N  = 1024;
constexpr int H  = 256;
constexpr int H2 = 512;
constexpr int NT = B * N;        // 16384 total nodes
constexpr int NE = N - 1;        // 1023 MST edges per batch
constexpr int CAP = 32;          // adjacency capacity per node (MST degree << 32)
constexpr int GEMM1_BLKS = (NT / 128) * 4;   // 512

__device__ __forceinline__ unsigned umin32(unsigned a, unsigned b) { return a < b ? a : b; }

typedef __attribute__((ext_vector_type(8))) short short8;
typedef __attribute__((ext_vector_type(4))) float f32x4;

// ---------------- row squared-norms + per-call flag clear -----------------------
__global__ void n2_kernel(const float* __restrict__ x, float* __restrict__ n2,
                          int* __restrict__ flags) {
  if (blockIdx.x == 0 && threadIdx.x < B) flags[threadIdx.x] = 0;  // reset each call
  int wave = threadIdx.x >> 6, lane = threadIdx.x & 63;
  int row  = blockIdx.x * 4 + wave;
  float4 v = *(const float4*)(x + (size_t)row * H + lane * 4);
  float s  = v.x * v.x + v.y * v.y + v.z * v.z + v.w * v.w;
  #pragma unroll
  for (int off = 32; off; off >>= 1) s += __shfl_xor(s, off);
  if (lane == 0) n2[row] = s;
}

// ------ distance matrix, symmetric upper-tri tiles; mirror via LDS transpose ----
__global__ __launch_bounds__(256) void dist_kernel(const float* __restrict__ x,
    const float* __restrict__ n2, float* __restrict__ dist) {
  __shared__ float sh[128][136];
  const int bb = blockIdx.z;
  int idx = blockIdx.x, ti = 0;
  while (idx >= 8 - ti) { idx -= 8 - ti; ++ti; }
  const int tj = ti + idx;
  const int i0 = ti * 128, j0 = tj * 128;
  const int t = threadIdx.x, tx = t & 15, ty = t >> 4;
  const float* xb = x + (size_t)bb * N * H;
  float acc[8][8] = {};
  for (int kc = 0; kc < H; kc += 16) {
    #pragma unroll
    for (int u = 0; u < 2; ++u) {
      int q = t + u * 256;
      int row = q >> 2, kf = (q & 3) * 4;
      float4 a = *(const float4*)(xb + (size_t)(i0 + row) * H + kc + kf);
      sh[kf + 0][row] = a.x; sh[kf + 1][row] = a.y;
      sh[kf + 2][row] = a.z; sh[kf + 3][row] = a.w;
      float4 bv = *(const float4*)(xb + (size_t)(j0 + row) * H + kc + kf);
      sh[16 + kf + 0][row] = bv.x; sh[16 + kf + 1][row] = bv.y;
      sh[16 + kf + 2][row] = bv.z; sh[16 + kf + 3][row] = bv.w;
    }
    __syncthreads();
    #pragma unroll
    for (int kk = 0; kk < 16; ++kk) {
      float4 a0 = *(const float4*)&sh[kk][ty * 4];
      float4 a1 = *(const float4*)&sh[kk][64 + ty * 4];
      float4 b0 = *(const float4*)&sh[16 + kk][tx * 4];
      float4 b1 = *(const float4*)&sh[16 + kk][64 + tx * 4];
      float ar[8] = {a0.x,a0.y,a0.z,a0.w,a1.x,a1.y,a1.z,a1.w};
      float br[8] = {b0.x,b0.y,b0.z,b0.w,b1.x,b1.y,b1.z,b1.w};
      #pragma unroll
      for (int r = 0; r < 8; ++r)
        #pragma unroll
        for (int c = 0; c < 8; ++c) acc[r][c] += ar[r] * br[c];
    }
    __syncthreads();
  }
  float n2i[8], n2j[8];
  #pragma unroll
  for (int r = 0; r < 8; ++r)
    n2i[r] = n2[bb * N + i0 + (r < 4 ? ty * 4 + r : 64 + ty * 4 + r - 4)];
  #pragma unroll
  for (int c = 0; c < 8; ++c)
    n2j[c] = n2[bb * N + j0 + (c < 4 ? tx * 4 + c : 64 + tx * 4 + c - 4)];
  const bool mirror = (ti != tj);
  float* distb = dist + (size_t)bb * N * N;
  #pragma unroll
  for (int r = 0; r < 8; ++r) {
    int rl = (r < 4 ? ty * 4 + r : 64 + ty * 4 + r - 4);
    float o[8];
    #pragma unroll
    for (int c = 0; c < 8; ++c) {
      float d2 = (n2i[r] + n2j[c]) - 2.0f * acc[r][c];
      o[c] = sqrtf(fmaxf(d2, 0.0f));
    }
    float* dst = distb + (size_t)(i0 + rl) * N + j0;
    *(float4*)(dst + tx * 4)      = make_float4(o[0], o[1], o[2], o[3]);
    *(float4*)(dst + 64 + tx * 4) = make_float4(o[4], o[5], o[6], o[7]);
    if (mirror) {                                   // stash for transpose
      *(float4*)&sh[rl][tx * 4]      = make_float4(o[0], o[1], o[2], o[3]);
      *(float4*)&sh[rl][64 + tx * 4] = make_float4(o[4], o[5], o[6], o[7]);
    }
  }
  if (mirror) {
    __syncthreads();                                // o-tile fully in sh
    const int q = t >> 1, half = (t & 1) * 64;      // transposed row q, half of cols
    float* gdst = distb + (size_t)(j0 + q) * N + i0 + half;
    #pragma unroll
    for (int s = 0; s < 64; s += 4) {
      float4 v;
      v.x = sh[half + s + 0][q];
      v.y = sh[half + s + 1][q];
      v.z = sh[half + s + 2][q];
      v.w = sh[half + s + 3][q];
      *(float4*)(gdst + s) = v;
    }
  }
}

// ---------------- Prim helpers -----------------------------------------------------
__device__ __forceinline__ unsigned wave_min_u32(unsigned x) {
  unsigned t;
  t = (unsigned)__builtin_amdgcn_update_dpp((int)x, (int)x, 0x111, 0xf, 0xf, false); x = umin32(x, t);
  t = (unsigned)__builtin_amdgcn_update_dpp((int)x, (int)x, 0x112, 0xf, 0xf, false); x = umin32(x, t);
  t = (unsigned)__builtin_amdgcn_update_dpp((int)x, (int)x, 0x114, 0xf, 0xf, false); x = umin32(x, t);
  t = (unsigned)__builtin_amdgcn_update_dpp((int)x, (int)x, 0x118, 0xf, 0xf, false); x = umin32(x, t);
  x = umin32(x, (unsigned)__shfl_xor((int)x, 16));
  x = umin32(x, (unsigned)__shfl_xor((int)x, 32));
  return (unsigned)__builtin_amdgcn_readlane((int)x, 63);
}

struct Sel2 { unsigned w; int j; };

// Parity-buffered block argmin: ONE barrier per call (R18, proven bit-exact).
__device__ __forceinline__ Sel2 block_select(unsigned mw0, unsigned mw1,
    unsigned mw2, unsigned mw3, int wid, int lane,
    unsigned long long (*smin)[4], int pb) {
  unsigned lm = umin32(umin32(mw0, mw1), umin32(mw2, mw3));
  unsigned wm = wave_min_u32(lm);
  unsigned mb = (mw0 == wm ? 1u : 0u) | (mw1 == wm ? 2u : 0u) |
                (mw2 == wm ? 4u : 0u) | (mw3 == wm ? 8u : 0u);
  unsigned long long bal = __ballot(mb != 0);
  int fl = __ffsll(bal) - 1;                         // lowest matching lane
  int slot = __ffs((unsigned)__builtin_amdgcn_readlane((int)mb, fl)) - 1;
  int widx = (wid << 8) | (fl << 2) | slot;          // lowest node id in wave
  if (lane == 0)
    smin[pb][wid] = ((unsigned long long)wm << 32) | (unsigned)widx;
  __syncthreads();                                   // writes visible
  unsigned long long k0 = smin[pb][0], k1 = smin[pb][1];
  unsigned long long k2 = smin[pb][2], k3 = smin[pb][3];
  unsigned long long ka = k0 < k1 ? k0 : k1;
  unsigned long long kb = k2 < k3 ? k2 : k3;
  unsigned long long kk = ka < kb ? ka : kb;
  Sel2 r; r.w = (unsigned)(kk >> 32); r.j = (int)(unsigned)(kk & 0xFFFFFFFFu);
  return r;
}

// ------- merged: blocks 0..15 = Prim; 16..527 = feat@W1; 528..543 = L2 warmers --
// Warmer i streams ONLY rows [0,512) of dist[batch i] (2 MiB): two warmed halves
// per XCD = 4 MiB = exactly one XCD L2, so the warmed half stays RESIDENT instead
// of thrashing (R19 warmed 2x4 MiB -> evictions ate most of the benefit).
// Warmers are read-only and gate nothing -> zero correctness surface.
__global__ __launch_bounds__(256) void prim_gemm1_kernel(
    const float* __restrict__ dist, const float* __restrict__ feat,
    const float* __restrict__ W1, int* __restrict__ ep, int* __restrict__ ev,
    float* __restrict__ ewt, float* __restrict__ y, int* __restrict__ flags) {
  __shared__ unsigned long long smin[2][4];
  __shared__ int epv[NE];
  __shared__ int evv[NE];
  __shared__ float ews[NE];
  __shared__ float As[16][132], Bs[16][132];
  if (blockIdx.x < B) {
    // ==================== Prim path (R18, byte-identical) ====================
    const int b = blockIdx.x;
    const int tid = threadIdx.x, wid = tid >> 6, lane = tid & 63;
    const float* Db = dist + (size_t)b * N * N;
    const int jbase = tid * 4;                        // this thread's 4 nodes

    unsigned d0, d1, d2, d3;
    {
      float4 v = *(const float4*)(Db + jbase);        // row 0
      d0 = __float_as_uint(v.x); d1 = __float_as_uint(v.y);
      d2 = __float_as_uint(v.z); d3 = __float_as_uint(v.w);
    }
    unsigned mw0 = d0, mw1 = d1, mw2 = d2, mw3 = d3;
    unsigned rm0 = 0, rm1 = 0, rm2 = 0, rm3 = 0;
    int pa0 = 0, pa1 = 0, pa2 = 0, pa3 = 0;
    if (tid == 0) { rm0 = ~0u; mw0 = ~0u; }           // node 0 in tree

    Sel2 s0 = block_select(mw0, mw1, mw2, mw3, wid, lane, smin, 0);
    int cj = s0.j;
    if ((cj >> 2) == tid) {
      int sl = cj & 3;
      int pv = pa0; if (sl == 1) pv = pa1; if (sl == 2) pv = pa2; if (sl == 3) pv = pa3;
      epv[0] = pv; evv[0] = cj; ews[0] = __uint_as_float(s0.w);
      if (sl == 0) { rm0 = ~0u; mw0 = ~0u; }
      if (sl == 1) { rm1 = ~0u; mw1 = ~0u; }
      if (sl == 2) { rm2 = ~0u; mw2 = ~0u; }
      if (sl == 3) { rm3 = ~0u; mw3 = ~0u; }
    }
    float4 xq = *(const float4*)(Db + (size_t)cj * N + jbase);

    for (int k = 1; k < NE; ++k) {
      unsigned r0 = __float_as_uint(xq.x), r1 = __float_as_uint(xq.y);
      unsigned r2 = __float_as_uint(xq.z), r3 = __float_as_uint(xq.w);
      unsigned q0 = r0 | rm0, q1 = r1 | rm1, q2 = r2 | rm2, q3 = r3 | rm3;
      mw0 = umin32(mw0, q0); mw1 = umin32(mw1, q1);
      mw2 = umin32(mw2, q2); mw3 = umin32(mw3, q3);
      Sel2 se = block_select(mw0, mw1, mw2, mw3, wid, lane, smin, k & 1);
      const int nj = se.j;
      float4 nxt = *(const float4*)(Db + (size_t)nj * N + jbase);
      if (r0 < d0) { pa0 = cj; d0 = r0; }             // strict <, matches reference
      if (r1 < d1) { pa1 = cj; d1 = r1; }
      if (r2 < d2) { pa2 = cj; d2 = r2; }
      if (r3 < d3) { pa3 = cj; d3 = r3; }
      if ((nj >> 2) == tid) {                         // owner: emit + mask
        int sl = nj & 3;
        int pv = pa0; if (sl == 1) pv = pa1; if (sl == 2) pv = pa2; if (sl == 3) pv = pa3;
        epv[k] = pv; evv[k] = nj; ews[k] = __uint_as_float(se.w);
        if (sl == 0) { rm0 = ~0u; mw0 = ~0u; }
        if (sl == 1) { rm1 = ~0u; mw1 = ~0u; }
        if (sl == 2) { rm2 = ~0u; mw2 = ~0u; }
        if (sl == 3) { rm3 = ~0u; mw3 = ~0u; }
      }
      cj = nj; xq = nxt;
    }

    __syncthreads();                                  // epv/evv/ews visible
    for (int e = tid; e < NE; e += 256) {
      ep[b * NE + e]  = epv[e];
      ev[b * NE + e]  = evv[e];
      ewt[b * NE + e] = ews[e];
    }
    if (tid == 0) atomicExch(&flags[b], 1);           // release warmer b
  } else if (blockIdx.x < B + GEMM1_BLKS) {
    // ==================== gemm1 path: y = feat @ W1 (raw, K=256) ==================
    const int gb = blockIdx.x - B;
    const int m0 = (gb >> 2) * 128, n0 = (gb & 3) * 128;
    const int t = threadIdx.x, tx = t & 15, ty = t >> 4;
    float acc[8][8] = {};
    for (int kc = 0; kc < H; kc += 16) {
      #pragma unroll
      for (int u = 0; u < 2; ++u) {
        int q = t + u * 256;
        int row = q >> 2, kf = (q & 3) * 4;
        float4 a = *(const float4*)(feat + (size_t)(m0 + row) * H + kc + kf);
        As[kf + 0][row] = a.x; As[kf + 1][row] = a.y;
        As[kf + 2][row] = a.z; As[kf + 3][row] = a.w;
        int rowB = q >> 5, cf = (q & 31) * 4;
        *(float4*)&Bs[rowB][cf] = *(const float4*)(W1 + (size_t)(kc + rowB) * H2 + n0 + cf);
      }
      __syncthreads();
      #pragma unroll
      for (int kk = 0; kk < 16; ++kk) {
        float4 a0 = *(const float4*)&As[kk][ty * 4];
        float4 a1 = *(const float4*)&As[kk][64 + ty * 4];
        float4 b0 = *(const float4*)&Bs[kk][tx * 4];
        float4 b1 = *(const float4*)&Bs[kk][64 + tx * 4];
        float ar[8] = {a0.x,a0.y,a0.z,a0.w,a1.x,a1.y,a1.z,a1.w};
        float br[8] = {b0.x,b0.y,b0.z,b0.w,b1.x,b1.y,b1.z,b1.w};
        #pragma unroll
        for (int r = 0; r < 8; ++r)
          #pragma unroll
          for (int c = 0; c < 8; ++c) acc[r][c] += ar[r] * br[c];
      }
      __syncthreads();
    }
    #pragma unroll
    for (int r = 0; r < 8; ++r) {
      int m = m0 + (r < 4 ? ty * 4 + r : 64 + ty * 4 + r - 4);
      float* dst = y + (size_t)m * H2 + n0;
      *(float4*)(dst + tx * 4)      = make_float4(acc[r][0], acc[r][1], acc[r][2], acc[r][3]);
      *(float4*)(dst + 64 + tx * 4) = make_float4(acc[r][4], acc[r][5], acc[r][6], acc[r][7]);
    }
  } else {
    // ==================== warmer path: keep HALF of dist[wb] L2-resident =========
    const int wb = blockIdx.x - (B + GEMM1_BLKS);     // 0..15; XCD (528+wb)%8 == wb%8
    const float* Dw = dist + (size_t)wb * N * N;      // rows [0,512) = 2 MiB
    volatile const int* flag = flags + wb;
    const int t = threadIdx.x;
    for (int pass = 0; pass < 32; ++pass) {           // hard cap: guaranteed exit
      if (*flag != 0) break;
      for (int off = 0; off < (N / 2) * N; off += 16384) {  // 64 KB chunks, 2 MiB total
        if (*flag != 0) break;
        float s = 0.0f;
        #pragma unroll
        for (int q = 0; q < 16; ++q) {                // 16 x 256thr x 16B = 64 KB
          float4 vv = *(const float4*)(Dw + off + q * 1024 + t * 4);
          s += vv.x + vv.y + vv.z + vv.w;
        }
        asm volatile("" :: "v"(s));                   // keep loads alive, no store
      }
    }
  }
}

// ---------------- adjacency + deg^-1/2 (R15, proven; 64-block parallel) ---------
__global__ void adj_kernel(const int* __restrict__ ep, const int* __restrict__ ev,
    const float* __restrict__ ewt, int* __restrict__ adjI, float* __restrict__ adjW,
    int* __restrict__ cnt, float* __restrict__ dinv) {
  int i = blockIdx.x * 256 + threadIdx.x;
  int b = i >> 10, loc = i & 1023;
  const int* epb = ep + b * NE;
  const int* evb = ev + b * NE;
  const float* ewb = ewt + b * NE;
  int c = 0; float wsum = 0.0f;
  for (int k = 0; k < NE; ++k) {
    int p = epb[k], v = evb[k];
    if (p == loc || v == loc) {
      float w = ewb[k];
      wsum += w;
      int nb = (p == loc) ? v : p;
      if (c < CAP) { adjI[i * CAP + c] = (b << 10) + nb; adjW[i * CAP + c] = w; }
      ++c;
    }
  }
  cnt[i]  = c < CAP ? c : CAP;
  dinv[i] = 1.0f / sqrtf(wsum + 1.0f);
}

// ------ finish layer 1: out1 = tanh(alpha*y + (1-alpha)*A_hat y + b1) -----------
__global__ void finish1_kernel(const float* __restrict__ y, const int* __restrict__ adjI,
    const float* __restrict__ adjW, const int* __restrict__ cnt,
    const float* __restrict__ dinv, const float* __restrict__ b1,
    float* __restrict__ out1) {
  int wave = threadIdx.x >> 6, lane = threadIdx.x & 63;
  int i = blockIdx.x * 4 + wave;
  float dv = dinv[i];
  int c = cnt[i];
  float selfc = ALPHA + (1.0f - ALPHA) * dv * dv;
  float4 acc[2];
  const float* yi = y + (size_t)i * H2 + lane * 4;
  #pragma unroll
  for (int u = 0; u < 2; ++u) {
    float4 v = *(const float4*)(yi + u * 256);
    acc[u].x = selfc * v.x; acc[u].y = selfc * v.y;
    acc[u].z = selfc * v.z; acc[u].w = selfc * v.w;
  }
  for (int e = 0; e < c; ++e) {
    int j   = adjI[i * CAP + e];
    float w = adjW[i * CAP + e];
    float coef = (1.0f - ALPHA) * dv * (w * dinv[j]);
    const float* yj = y + (size_t)j * H2 + lane * 4;
    #pragma unroll
    for (int u = 0; u < 2; ++u) {
      float4 v = *(const float4*)(yj + u * 256);
      acc[u].x += coef * v.x; acc[u].y += coef * v.y;
      acc[u].z += coef * v.z; acc[u].w += coef * v.w;
    }
  }
  float* ho = out1 + (size_t)i * H2 + lane * 4;
  #pragma unroll
  for (int u = 0; u < 2; ++u) {
    float4 bb = *(const float4*)(b1 + lane * 4 + u * 256);
    float4 o;
    o.x = tanhf(acc[u].x + bb.x); o.y = tanhf(acc[u].y + bb.y);
    o.z = tanhf(acc[u].z + bb.z); o.w = tanhf(acc[u].w + bb.w);
    *(float4*)(ho + u * 256) = o;
  }
}

// ---------------- SSG propagation: h = alpha*x + (1-alpha)*A_hat x --------------
template <int HH>
__global__ void prop_kernel(const float* __restrict__ x, const int* __restrict__ adjI,
    const float* __restrict__ adjW, const int* __restrict__ cnt,
    const float* __restrict__ dinv, float* __restrict__ h) {
  constexpr int U = HH / 256;
  int wave = threadIdx.x >> 6, lane = threadIdx.x & 63;
  int i = blockIdx.x * 4 + wave;
  float dv = dinv[i];
  int c = cnt[i];
  float selfc = ALPHA + (1.0f - ALPHA) * dv * dv;
  float4 acc[U];
  const float* xi = x + (size_t)i * HH + lane * 4;
  #pragma unroll
  for (int u = 0; u < U; ++u) {
    float4 v = *(const float4*)(xi + u * 256);
    acc[u].x = selfc * v.x; acc[u].y = selfc * v.y;
    acc[u].z = selfc * v.z; acc[u].w = selfc * v.w;
  }
  for (int e = 0; e < c; ++e) {
    int j   = adjI[i * CAP + e];
    float w = adjW[i * CAP + e];
    float coef = (1.0f - ALPHA) * dv * (w * dinv[j]);
    const float* xj = x + (size_t)j * HH + lane * 4;
    #pragma unroll
    for (int u = 0; u < U; ++u) {
      float4 v = *(const float4*)(xj + u * 256);
      acc[u].x += coef * v.x; acc[u].y += coef * v.y;
      acc[u].z += coef * v.z; acc[u].w += coef * v.w;
    }
  }
  float* ho = h + (size_t)i * HH + lane * 4;
  #pragma unroll
  for (int u = 0; u < U; ++u) *(float4*)(ho + u * 256) = acc[u];
}

// ---- split fp32 -> (hi, lo) bf16 (truncation; a - hi is exact in fp32) ---------
__device__ __forceinline__ void bf16split(float a, unsigned short& hi, unsigned short& lo) {
  unsigned u = __float_as_uint(a);
  hi = (unsigned short)(u >> 16);
  float fh = __uint_as_float(u & 0xFFFF0000u);
  float fl = a - fh;
  lo = (unsigned short)(__float_as_uint(fl) >> 16);
}

// ---- MFMA split-bf16 GEMM + bias + tanh (R15, proven) --------------------------
__global__ __launch_bounds__(256) void mgemm_tanh_kernel(const float* __restrict__ A,
    const float* __restrict__ W, const float* __restrict__ bias, float* __restrict__ C) {
  __shared__ unsigned short Ahi[128][40], Alo[128][40];   // [row][k]
  __shared__ unsigned short Bhi[128][40], Blo[128][40];   // [col][k] (W transposed)
  const int m0 = blockIdx.x * 128, n0 = blockIdx.y * 128;
  const int t = threadIdx.x;
  const int w = t >> 6, lane = t & 63;
  const int lrow = lane & 15, lk = (lane >> 4) * 8;
  f32x4 acc[2][8];
  #pragma unroll
  for (int mt = 0; mt < 2; ++mt)
    #pragma unroll
    for (int nt = 0; nt < 8; ++nt) acc[mt][nt] = (f32x4){0.f, 0.f, 0.f, 0.f};

  const int arow = t >> 1, akq = (t & 1) * 16;            // A staging coords
  const int wr = t & 31, wc4 = (t >> 5) * 16;             // W staging coords

  for (int kc = 0; kc < H2; kc += 32) {
    {
      const float* src = A + (size_t)(m0 + arow) * H2 + kc + akq;
      unsigned short h[16], l[16];
      #pragma unroll
      for (int i = 0; i < 16; i += 4) {
        float4 v = *(const float4*)(src + i);
        bf16split(v.x, h[i], l[i]);     bf16split(v.y, h[i+1], l[i+1]);
        bf16split(v.z, h[i+2], l[i+2]); bf16split(v.w, h[i+3], l[i+3]);
      }
      short8 ph0 = {(short)h[0],(short)h[1],(short)h[2],(short)h[3],
                    (short)h[4],(short)h[5],(short)h[6],(short)h[7]};
      short8 ph1 = {(short)h[8],(short)h[9],(short)h[10],(short)h[11],
                    (short)h[12],(short)h[13],(short)h[14],(short)h[15]};
      short8 pl0 = {(short)l[0],(short)l[1],(short)l[2],(short)l[3],
                    (short)l[4],(short)l[5],(short)l[6],(short)l[7]};
      short8 pl1 = {(short)l[8],(short)l[9],(short)l[10],(short)l[11],
                    (short)l[12],(short)l[13],(short)l[14],(short)l[15]};
      *(short8*)&Ahi[arow][akq]     = ph0;
      *(short8*)&Ahi[arow][akq + 8] = ph1;
      *(short8*)&Alo[arow][akq]     = pl0;
      *(short8*)&Alo[arow][akq + 8] = pl1;
    }
    {
      const float* wsrc = W + (size_t)(kc + wr) * H2 + n0 + wc4;
      #pragma unroll
      for (int i = 0; i < 16; i += 4) {
        float4 v = *(const float4*)(wsrc + i);
        unsigned short h0,h1,h2,h3,l0,l1,l2,l3;
        bf16split(v.x, h0, l0); bf16split(v.y, h1, l1);
        bf16split(v.z, h2, l2); bf16split(v.w, h3, l3);
        Bhi[wc4+i+0][wr] = h0; Bhi[wc4+i+1][wr] = h1;
        Bhi[wc4+i+2][wr] = h2; Bhi[wc4+i+3][wr] = h3;
        Blo[wc4+i+0][wr] = l0; Blo[wc4+i+1][wr] = l1;
        Blo[wc4+i+2][wr] = l2; Blo[wc4+i+3][wr] = l3;
      }
    }
    __syncthreads();
    const int r0 = w * 32 + lrow;
    short8 a0h = *(const short8*)&Ahi[r0][lk];
    short8 a0l = *(const short8*)&Alo[r0][lk];
    short8 a1h = *(const short8*)&Ahi[r0 + 16][lk];
    short8 a1l = *(const short8*)&Alo[r0 + 16][lk];
    #pragma unroll
    for (int nt = 0; nt < 8; ++nt) {
      short8 bh = *(const short8*)&Bhi[nt * 16 + lrow][lk];
      short8 bl = *(const short8*)&Blo[nt * 16 + lrow][lk];
      acc[0][nt] = __builtin_amdgcn_mfma_f32_16x16x32_bf16(a0h, bh, acc[0][nt], 0, 0, 0);
      acc[0][nt] = __builtin_amdgcn_mfma_f32_16x16x32_bf16(a0l, bh, acc[0][nt], 0, 0, 0);
      acc[0][nt] = __builtin_amdgcn_mfma_f32_16x16x32_bf16(a0h, bl, acc[0][nt], 0, 0, 0);
      acc[1][nt] = __builtin_amdgcn_mfma_f32_16x16x32_bf16(a1h, bh, acc[1][nt], 0, 0, 0);
      acc[1][nt] = __builtin_amdgcn_mfma_f32_16x16x32_bf16(a1l, bh, acc[1][nt], 0, 0, 0);
      acc[1][nt] = __builtin_amdgcn_mfma_f32_16x16x32_bf16(a1h, bl, acc[1][nt], 0, 0, 0);
    }
    __syncthreads();
  }
  #pragma unroll
  for (int mt = 0; mt < 2; ++mt) {
    #pragma unroll
    for (int nt = 0; nt < 8; ++nt) {
      int col = n0 + nt * 16 + lrow;
      float bcol = bias[col];
      #pragma unroll
      for (int i = 0; i < 4; ++i) {
        int row = m0 + w * 32 + mt * 16 + (lane >> 4) * 4 + i;
        C[(size_t)row * H2 + col] = tanhf(acc[mt][nt][i] + bcol);
      }
    }
  }
}

// ---- fused mean-pool + dense head (R18, proven bit-exact) ----------------------
__global__ void pool_head_kernel(const float* __restrict__ x,
    const float* __restrict__ Wd, const float* __restrict__ bd,
    const float* __restrict__ Wo, const float* __restrict__ bo,
    float* __restrict__ out) {
  __shared__ float sp[512], shh[256];
  int b = blockIdx.x, t = threadIdx.x;
  const float* xb = x + ((size_t)b << 10) * H2;
  float s0 = 0.0f, s1 = 0.0f;
  for (int i = 0; i < N; ++i) {
    s0 += xb[(size_t)i * H2 + t];
    s1 += xb[(size_t)i * H2 + t + 256];
  }
  sp[t] = s0 * (1.0f / N);
  sp[t + 256] = s1 * (1.0f / N);
  __syncthreads();
  float acc = bd[t];
  for (int c2 = 0; c2 < 512; ++c2) acc += sp[c2] * Wd[c2 * 256 + t];
  shh[t] = tanhf(acc);
  __syncthreads();
  if (t < 8) {
    float o = bo[t];
    for (int j = 0; j < 256; ++j) o += shh[j] * Wo[j * 8 + t];
    out[b * 8 + t] = o;
  }
}

}  // namespace

extern "C" void kernel_launch(void* const* d_in, const int* in_sizes, int n_in,
                              void* d_out, int out_size, void* d_ws, size_t ws_size,
                              hipStream_t stream) {
  const float* feat = (const float*)d_in[0];
  const float* W1 = (const float*)d_in[1];
  const float* b1 = (const float*)d_in[2];
  const float* W2 = (const float*)d_in[3];
  const float* b2 = (const float*)d_in[4];
  const float* W3 = (const float*)d_in[5];
  const float* b3 = (const float*)d_in[6];
  const float* Wd = (const float*)d_in[7];
  const float* bd = (const float*)d_in[8];
  const float* Wo = (const float*)d_in[9];
  const float* bo = (const float*)d_in[10];
  float* out = (float*)d_out;
  char* ws = (char*)d_ws;

  float* dist = (float*)(ws);
  float* out1 = (float*)(ws);
  float* x2   = (float*)(ws + ((size_t)32 << 20));
  float* x3   = (float*)(ws);
  float* ybuf = (float*)(ws + ((size_t)64 << 20));
  float* hbuf = (float*)(ws + ((size_t)64 << 20));
  char* misc  = ws + ((size_t)96 << 20);
  int*   ep     = (int*)(misc);
  int*   ev     = (int*)(misc + 65536);
  float* ewt    = (float*)(misc + 131072);
  int*   cnt    = (int*)(misc + 196608);
  float* dinv   = (float*)(misc + 262144);
  int*   adjI   = (int*)(misc + 327680);
  float* adjW   = (float*)(misc + 327680 + 2097152);
  float* n2     = (float*)(misc + 327680 + 2 * 2097152);
  int*   flags  = (int*)(misc + 327680 + 2 * 2097152 + 65536);

  n2_kernel<<<NT / 4, 256, 0, stream>>>(feat, n2, flags);
  dist_kernel<<<dim3(36, 1, 16), 256, 0, stream>>>(feat, n2, dist);
  prim_gemm1_kernel<<<B + GEMM1_BLKS + B, 256, 0, stream>>>(
      dist, feat, W1, ep, ev, ewt, ybuf, flags);
  adj_kernel<<<NT / 256, 256, 0, stream>>>(ep, ev, ewt, adjI, adjW, cnt, dinv);

  finish1_kernel<<<NT / 4, 256, 0, stream>>>(ybuf, adjI, adjW, cnt, dinv, b1, out1);
  prop_kernel<512><<<NT / 4, 256, 0, stream>>>(out1, adjI, adjW, cnt, dinv, hbuf);
  mgemm_tanh_kernel<<<dim3(NT / 128, 4), 256, 0, stream>>>(hbuf, W2, b2, x2);
  prop_kernel<512><<<NT / 4, 256, 0, stream>>>(x2, adjI, adjW, cnt, dinv, hbuf);
  mgemm_tanh_kernel<<<dim3(NT / 128, 4), 256, 0, stream>>>(hbuf, W3, b3, x3);

  pool_head_kernel<<<B, 256, 0, stream>>>(x3, Wd, bd, Wo, bo, out);
}